// Round 16
// baseline (7331.528 us; speedup 1.0000x reference)
//
#include <hip/hip_runtime.h>
#include <hip/hip_bf16.h>
#include <math.h>

#define EDIM   1024
#define TSEQ   512
#define NBATCH 2
#define NHEAD  16
#define HDIM   64
#define NLAYER 24
#define VOCAB  8124
#define DFFDIM 2730
#define DPAD   2752              // 43*64 padded SwiGLU width
#define MTOK   (NBATCH*TSEQ)     // 1024
#define NELEM  (MTOK*EDIM)
#define EPSF   1e-5f
#define SCALEF (1.0f/32.0f)
#define NEGBIG (-1e30f)
#define LCONV  3088              // conv tiles per layer
#define ACONV  (NLAYER*LCONV)    // 74112, then head tiles follow
#define HCONV  2048

typedef __bf16 bf16x8 __attribute__((ext_vector_type(8)));
typedef __bf16 bf16x4 __attribute__((ext_vector_type(4)));
typedef float  f32x4  __attribute__((ext_vector_type(4)));

#define MFMA(a, b, c) __builtin_amdgcn_mfma_f32_16x16x32_bf16((a), (b), (c), 0, 0, 0)

__device__ __forceinline__ void gl_lds16(const __bf16* g, __bf16* l) {
  __builtin_amdgcn_global_load_lds(
      (const __attribute__((address_space(1))) void*)g,
      (__attribute__((address_space(3))) void*)l, 16, 0, 0);
}
template <int N> __device__ __forceinline__ void vmwait() {
  asm volatile("s_waitcnt vmcnt(%0)" :: "n"(N) : "memory");
}
__device__ __forceinline__ void lgkm_barrier() {
  asm volatile("s_waitcnt lgkmcnt(0)" ::: "memory");
  __builtin_amdgcn_s_barrier();
}

// ---------------- weight pointers bundle (for carrier conv blocks)
struct ConvW {
  const float *Wqkv, *Wo, *W1, *W3, *W2w, *g_mha, *g_ff, *Wout, *g_final;
  __bf16 *qkvT, *woT, *w1T, *w3T, *w2T, *WoutT;
};

// ---------------------------------------------------------------- embedding+PE
__global__ __launch_bounds__(256) void k_embed(const int* __restrict__ tok,
                                               const float* __restrict__ emb,
                                               float* __restrict__ x) {
  const int bt = blockIdx.x;
  const int t  = bt & (TSEQ - 1);
  const int tk = tok[bt];
  const float* er = emb + (size_t)tk * EDIM;
  float* xr = x + (size_t)bt * EDIM;
  for (int e = threadIdx.x * 4; e < EDIM; e += 256 * 4) {
    float4 v = *(const float4*)(er + e);
    float vv[4] = {v.x, v.y, v.z, v.w};
    float ou[4];
#pragma unroll
    for (int j = 0; j < 4; ++j) {
      int ee = e + j;
      int i2 = ee & ~1;
      float freq = expf(-(float)i2 * (9.210340371976184f / 1024.0f));
      float ang  = (float)t * freq;
      ou[j] = vv[j] + ((ee & 1) ? cosf(ang) : sinf(ang));
    }
    *(float4*)(xr + e) = make_float4(ou[0], ou[1], ou[2], ou[3]);
  }
}

// ----------------- one-time RMS reduce + emit bf16(x) (layer-0 entry)
__global__ __launch_bounds__(256) void k_red1f(const float* __restrict__ x,
                                               float* __restrict__ part,
                                               __bf16* __restrict__ ybf) {
  const int tid = threadIdx.x;
  float s = 0.f;
  for (int i = (blockIdx.x * 256 + tid) * 4; i < NELEM; i += 256 * 256 * 4) {
    float4 v = *(const float4*)(x + i);
    bf16x4 o = {(__bf16)v.x, (__bf16)v.y, (__bf16)v.z, (__bf16)v.w};
    *(bf16x4*)(ybf + i) = o;
    s += v.x * v.x + v.y * v.y + v.z * v.z + v.w * v.w;
  }
#pragma unroll
  for (int o = 32; o > 0; o >>= 1) s += __shfl_down(s, o);
  __shared__ float sm[4];
  if ((tid & 63) == 0) sm[tid >> 6] = s;
  __syncthreads();
  if (tid == 0) part[blockIdx.x] = sm[0] + sm[1] + sm[2] + sm[3];
}

// ------------------------------------------------- weight convert + transpose
__device__ void conv_tile(const float* __restrict__ src,
                          const float* __restrict__ gk,
                          __bf16* __restrict__ dst,
                          int K, int N, int Kpad, int tk, int tn, char* smv) {
  float (*st)[65] = (float (*)[65])smv;   // 64 x 65 f32 = 16,640 B
  const int k0 = tk << 6, n0 = tn << 6;
  const int tid = threadIdx.x;
  {
    const int r0 = tid >> 4, c4 = (tid & 15) << 2;
#pragma unroll
    for (int i = 0; i < 4; ++i) {
      const int r = r0 + i * 16;
      const int k = k0 + r;
      f32x4 v = {0.f, 0.f, 0.f, 0.f};
      if (k < K) {
        const float* sp = src + (size_t)k * N + n0 + c4;
        if (n0 + c4 + 3 < N) v = __builtin_nontemporal_load((const f32x4*)sp);
        else {
          if (n0 + c4 + 0 < N) v[0] = sp[0];
          if (n0 + c4 + 1 < N) v[1] = sp[1];
          if (n0 + c4 + 2 < N) v[2] = sp[2];
          if (n0 + c4 + 3 < N) v[3] = sp[3];
        }
        if (gk) {
          const float gv = gk[k];
          v[0] *= gv; v[1] *= gv; v[2] *= gv; v[3] *= gv;
        }
      }
      st[r][c4 + 0] = v[0]; st[r][c4 + 1] = v[1];
      st[r][c4 + 2] = v[2]; st[r][c4 + 3] = v[3];
    }
  }
  __syncthreads();
  {
    const int nl0 = tid >> 3, c8 = (tid & 7) << 3;
#pragma unroll
    for (int i = 0; i < 2; ++i) {
      const int nl = nl0 + i * 32;
      bf16x8 o = {(__bf16)st[c8 + 0][nl], (__bf16)st[c8 + 1][nl],
                  (__bf16)st[c8 + 2][nl], (__bf16)st[c8 + 3][nl],
                  (__bf16)st[c8 + 4][nl], (__bf16)st[c8 + 5][nl],
                  (__bf16)st[c8 + 6][nl], (__bf16)st[c8 + 7][nl]};
      *(bf16x8*)&dst[(size_t)(n0 + nl) * Kpad + k0 + c8] = o;
    }
  }
}

__device__ void conv_dispatch(int g, const ConvW& cw, char* sm) {
  if (g < ACONV) {
    const int l = g / LCONV;
    int b = g - l * LCONV;
    if (b < 768) {
      conv_tile(cw.Wqkv + (size_t)l * 1024 * 3072, cw.g_mha + (size_t)l * EDIM,
                cw.qkvT + (size_t)l * 3072 * 1024, 1024, 3072, 1024,
                b / 48, b % 48, sm);
    } else if (b < 1024) {
      int t = b - 768;
      conv_tile(cw.Wo + (size_t)l * 1024 * 1024, nullptr,
                cw.woT + (size_t)l * 1024 * 1024, 1024, 1024, 1024,
                t / 16, t % 16, sm);
    } else if (b < 1712) {
      int t = b - 1024;
      conv_tile(cw.W1 + (size_t)l * 1024 * DFFDIM, cw.g_ff + (size_t)l * EDIM,
                cw.w1T + (size_t)l * DPAD * 1024, 1024, DFFDIM, 1024,
                t / 43, t % 43, sm);
    } else if (b < 2400) {
      int t = b - 1712;
      conv_tile(cw.W3 + (size_t)l * 1024 * DFFDIM, cw.g_ff + (size_t)l * EDIM,
                cw.w3T + (size_t)l * DPAD * 1024, 1024, DFFDIM, 1024,
                t / 43, t % 43, sm);
    } else {
      int t = b - 2400;
      conv_tile(cw.W2w + (size_t)l * DFFDIM * 1024, nullptr,
                cw.w2T + (size_t)l * 1024 * DPAD, DFFDIM, 1024, DPAD,
                t / 16, t % 16, sm);
    }
  } else {
    const int t = g - ACONV;
    conv_tile(cw.Wout, cw.g_final, cw.WoutT, 1024, VOCAB, 1024,
              t >> 7, t & 127, sm);
  }
}

__global__ __launch_bounds__(256) void k_conv0(ConvW cw) {
  __shared__ __align__(16) char sm[16640];
  conv_dispatch(blockIdx.x, cw, sm);
}

// ================================================================ MFMA GEMM
// BM=128, BN in {64,128}; BK=64; 4 waves, wave tile 64 x BN/2.
// A/B bf16 via global_load_lds, counted-vmcnt double buffer. Flattened 1D
// grid; blocks past nx*ny*gz run carrier conv tiles.
// MODE 0: qkv scatter (SC epilogue)
// MODE 1: split-K, LAST block per tile folds partials+bias+residual into x,
//         emits ybf=bf16(x) and per-tile sum(x^2) -> part_out[tile].
// MODE 2: SwiGLU dual (SC epilogue)
// MODE 3: head f32 out (SC epilogue)
template <int BN, int MODE, int SC>
__global__ __launch_bounds__(256) void mm(
    const __bf16* __restrict__ A,
    const __bf16* __restrict__ B0w, const __bf16* __restrict__ B1w,
    const float* __restrict__ bias0, const float* __restrict__ bias1,
    const float* __restrict__ part, int pcount,
    float* __restrict__ po, __bf16* __restrict__ ob,
    __bf16* __restrict__ qout, __bf16* __restrict__ kout, __bf16* __restrict__ vout,
    float* __restrict__ xres, float* __restrict__ part_out, int* __restrict__ cnt,
    int N, int lda, int ldb, int Ktot,
    int nx, int ny, int gz, ConvW cw, int convoff) {
  constexpr int DUAL = (MODE == 2) ? 2 : 1;
  constexpr int FN = BN / 32;
  constexpr int BL = (BN == 128) ? 4 : 2 * DUAL;
  constexpr int ASZ = 32768;                 // [2][8][128][8] bf16
  constexpr int BSZ = DUAL * BN * 256;       // [2][DUAL][8][BN][8] bf16
  __shared__ __align__(16) char smem[ASZ + BSZ];
  const int bid = blockIdx.x;
  const int ncomp = nx * ny * gz;
  if (bid >= ncomp) {
    conv_dispatch(convoff + (bid - ncomp), cw, smem);
    return;
  }
  typedef __bf16 (*AsP)[8][128][8];
  typedef __bf16 (*BsP)[DUAL][8][BN][8];
  AsP As = (AsP)smem;
  BsP Bs = (BsP)(smem + ASZ);
  const int bz = bid / (nx * ny);
  const int r2 = bid - bz * nx * ny;
  const int by = r2 / nx, bx = r2 - by * nx;
  const int tid = threadIdx.x, lane = tid & 63, wave = tid >> 6;
  const int m0 = by << 7, n0 = bx * BN;
  const int wm0 = (wave >> 1) * 64, wn0 = (wave & 1) * (BN / 2);
  const int lr = lane & 15, kh = lane >> 4;

  const int ktiles = Ktot >> 6;
  const int nt0 = (ktiles + gz - 1) / gz;
  const int tbeg = bz * nt0;
  const int tend = (ktiles < tbeg + nt0) ? ktiles : (tbeg + nt0);
  const int nt = tend - tbeg;

  f32x4 acc[DUAL][4][FN];
#pragma unroll
  for (int d = 0; d < DUAL; ++d)
#pragma unroll
    for (int mi = 0; mi < 4; ++mi)
#pragma unroll
      for (int fn = 0; fn < FN; ++fn) acc[d][mi][fn] = (f32x4){0.f, 0.f, 0.f, 0.f};

  auto STAGE = [&](int buf, int t) {
    const int k0 = (tbeg + t) << 6;
#pragma unroll
    for (int i = 0; i < 4; ++i) {
      const int d = i * 256 + tid;
      gl_lds16(A + (size_t)(m0 + (d & 127)) * lda + k0 + (d >> 7) * 8,
               &As[buf][d >> 7][d & 127][0]);
    }
    if (BN == 128) {
#pragma unroll
      for (int i = 0; i < 4; ++i) {
        const int d = i * 256 + tid;
        gl_lds16(B0w + (size_t)(n0 + (d & 127)) * ldb + k0 + (d >> 7) * 8,
                 &Bs[buf][0][d >> 7][d & 127][0]);
      }
    } else {
#pragma unroll
      for (int i = 0; i < 2; ++i) {
        const int d = i * 256 + tid;
        gl_lds16(B0w + (size_t)(n0 + (d & 63)) * ldb + k0 + (d >> 6) * 8,
                 &Bs[buf][0][d >> 6][d & 63][0]);
      }
      if (DUAL == 2) {
#pragma unroll
        for (int i = 0; i < 2; ++i) {
          const int d = i * 256 + tid;
          gl_lds16(B1w + (size_t)(n0 + (d & 63)) * ldb + k0 + (d >> 6) * 8,
                   &Bs[buf][DUAL - 1][d >> 6][d & 63][0]);
        }
      }
    }
  };
  auto COMP = [&](int buf) {
#pragma unroll
    for (int ks = 0; ks < 2; ++ks) {
      const int kidx = ks * 4 + kh;
      bf16x8 af[4];
#pragma unroll
      for (int mi = 0; mi < 4; ++mi)
        af[mi] = *(const bf16x8*)&As[buf][kidx][wm0 + mi * 16 + lr][0];
#pragma unroll
      for (int d = 0; d < DUAL; ++d)
#pragma unroll
        for (int fn = 0; fn < FN; ++fn) {
          bf16x8 bfr = *(const bf16x8*)&Bs[buf][d][kidx][wn0 + fn * 16 + lr][0];
#pragma unroll
          for (int mi = 0; mi < 4; ++mi)
            acc[d][mi][fn] = MFMA(af[mi], bfr, acc[d][mi][fn]);
        }
    }
  };

  STAGE(0, 0);
  int cur = 0;
  for (int t = 0; t < nt - 1; ++t) {
    STAGE(cur ^ 1, t + 1);          // next tile stays in flight
    vmwait<4 + BL>();               // own tile-t loads retired
    __builtin_amdgcn_s_barrier();
    COMP(cur);
    __builtin_amdgcn_s_barrier();
    cur ^= 1;
  }
  vmwait<0>();
  __builtin_amdgcn_s_barrier();
  COMP(cur);

  float sc = 1.0f;
  if (SC) {
    __shared__ float smr[4];
    float s = (tid < pcount) ? part[tid] : 0.f;
#pragma unroll
    for (int o = 32; o > 0; o >>= 1) s += __shfl_down(s, o);
    if ((tid & 63) == 0) smr[tid >> 6] = s;
    __syncthreads();
    sc = 1.0f / sqrtf((smr[0] + smr[1] + smr[2] + smr[3]) / (float)NELEM + EPSF);
  }

#pragma unroll
  for (int mi = 0; mi < 4; ++mi)
#pragma unroll
    for (int fn = 0; fn < FN; ++fn) {
      const int col = n0 + wn0 + fn * 16 + lr;
      if (MODE == 0) {
        const float bs = bias0[col];
        const int h = col / (3 * HDIM);
        const int rsel = (col >> 6) % 3;
        const int s2 = col & (HDIM - 1);
#pragma unroll
        for (int j = 0; j < 4; ++j) {
          const int row = m0 + wm0 + mi * 16 + (kh << 2) + j;
          const int b = row >> 9, t = row & (TSEQ - 1);
          const float v = acc[0][mi][fn][j] * sc + bs;
          if (rsel == 0)      qout[((size_t)(b * NHEAD + h) * TSEQ + t) * HDIM + s2] = (__bf16)v;
          else if (rsel == 1) kout[((size_t)(b * NHEAD + h) * TSEQ + t) * HDIM + s2] = (__bf16)v;
          else                vout[((size_t)(b * NHEAD + h) * HDIM + s2) * TSEQ + t] = (__bf16)v;
        }
      } else if (MODE == 1) {
        float* pz = po + (size_t)bz * NELEM;
#pragma unroll
        for (int j = 0; j < 4; ++j) {
          const int row = m0 + wm0 + mi * 16 + (kh << 2) + j;
          pz[(size_t)row * EDIM + col] = acc[0][mi][fn][j];
        }
      } else if (MODE == 2) {
        const bool ok = col < N;
        const float bb1 = ok ? bias0[col] : 0.f;
        const float bb3 = ok ? bias1[col] : 0.f;
#pragma unroll
        for (int j = 0; j < 4; ++j) {
          const int row = m0 + wm0 + mi * 16 + (kh << 2) + j;
          float v = 0.f;
          if (ok) {
            const float a1v = acc[0][mi][fn][j] * sc + bb1;
            const float a3v = acc[DUAL - 1][mi][fn][j] * sc + bb3;
            v = a1v * (1.0f / (1.0f + __expf(-a1v))) * a3v;
          }
          ob[(size_t)row * DPAD + col] = (__bf16)v;
        }
      } else {
        if (col < N) {
          const float bs = bias0[col];
#pragma unroll
          for (int j = 0; j < 4; ++j) {
            const int row = m0 + wm0 + mi * 16 + (kh << 2) + j;
            po[(size_t)row * N + col] = acc[0][mi][fn][j] * sc + bs;
          }
        }
      }
    }

  if (MODE == 1) {
    // ---- last-arriver folds: x += sum(partials) + bias; ybf; sum(x^2)
    const int tile = by * nx + bx;            // < 128
    __threadfence();                          // flush partial stores (device)
    __syncthreads();
    __shared__ int own;
    if (tid == 0) {
      const int old = atomicAdd(&cnt[tile], 1);
      own = (old == gz - 1) ? 1 : 0;
      if (own) atomicExch(&cnt[tile], 0);     // reset for next use
    }
    __syncthreads();
    if (!own) return;
    __threadfence();                          // acquire: see others' partials
    float ssum = 0.f;
#pragma unroll
    for (int i = 0; i < 8; ++i) {
      const int idx = i * 256 + tid;          // 0..2047
      const int row = m0 + (idx >> 4);
      const int c4  = n0 + ((idx & 15) << 2);
      f32x4 v = *(const f32x4*)(xres + (size_t)row * EDIM + c4);
      for (int z = 0; z < gz; ++z) {
        f32x4 p = *(const f32x4*)(po + (size_t)z * NELEM + (size_t)row * EDIM + c4);
        v[0] += p[0]; v[1] += p[1]; v[2] += p[2]; v[3] += p[3];
      }
      const f32x4 bb = *(const f32x4*)(bias0 + c4);
      v[0] += bb[0]; v[1] += bb[1]; v[2] += bb[2]; v[3] += bb[3];
      *(f32x4*)(xres + (size_t)row * EDIM + c4) = v;
      bf16x4 o = {(__bf16)v[0], (__bf16)v[1], (__bf16)v[2], (__bf16)v[3]};
      *(bf16x4*)(ob + (size_t)row * EDIM + c4) = o;
      ssum += v[0] * v[0] + v[1] * v[1] + v[2] * v[2] + v[3] * v[3];
    }
#pragma unroll
    for (int o = 32; o > 0; o >>= 1) ssum += __shfl_down(ssum, o);
    __shared__ float smf[4];
    if ((tid & 63) == 0) smf[tid >> 6] = ssum;
    __syncthreads();
    if (tid == 0) part_out[tile] = smf[0] + smf[1] + smf[2] + smf[3];
  }
}

// ------------------------------------------------- flash attention (bf16 in)
__global__ __launch_bounds__(256) void k_flash(const __bf16* __restrict__ qbuf,
                                               const __bf16* __restrict__ kbuf,
                                               const __bf16* __restrict__ vbufT,
                                               __bf16* __restrict__ y2,
                                               ConvW cw, int convoff) {
  __shared__ __align__(16) char smem[41472];
  const int bid = blockIdx.x;
  if (bid >= 512) {
    conv_dispatch(convoff + (bid - 512), cw, smem);
    return;
  }
  const int qt = bid & 15, bh = bid >> 4;
  const int b = bh >> 4, h = bh & 15;
  const int m0 = qt << 5;
  const __bf16* qp = qbuf  + (size_t)bh * TSEQ * HDIM;
  const __bf16* kp = kbuf  + (size_t)bh * TSEQ * HDIM;
  const __bf16* vp = vbufT + (size_t)bh * HDIM * TSEQ;   // [d][t]
  __bf16 (*Qs)[32][8]    = (__bf16 (*)[32][8])smem;                    // 4KB
  __bf16 (*Ks)[8][64][8] = (__bf16 (*)[8][64][8])(smem + 4096);        // 16KB
  __bf16 (*Vs)[8][64][8] = (__bf16 (*)[8][64][8])(smem + 20480);       // 16KB
  __bf16 (*Ps)[32][8]    = (__bf16 (*)[32][8])(smem + 36864);          // 4KB
  float* wmaxp = (float*)(smem + 40960);                               // [2][32]
  float* wsump = wmaxp + 64;                                           // [2][32]
  const int tid = threadIdx.x, lane = tid & 63, wave = tid >> 6;
  const int wm = (wave >> 1) << 4, wn = (wave & 1) << 5;
  const int lr = lane & 15, kh = lane >> 4;

  auto STAGE_KV = [&](int kt2, int buf) {
    const int n0s = kt2 << 6;
#pragma unroll
    for (int i = 0; i < 2; ++i) {
      const int d = i * 256 + tid;
      const int kb2 = d >> 6, row = d & 63;
      gl_lds16(kp + (size_t)(n0s + row) * HDIM + kb2 * 8, &Ks[buf][kb2][row][0]);
      gl_lds16(vp + (size_t)row * TSEQ + n0s + kb2 * 8, &Vs[buf][kb2][row][0]);
    }
  };

  gl_lds16(qp + (size_t)(m0 + (tid & 31)) * HDIM + (tid >> 5) * 8,
           &Qs[tid >> 5][tid & 31][0]);
  STAGE_KV(0, 0);

  float m_[4], l_[4];
#pragma unroll
  for (int j = 0; j < 4; ++j) { m_[j] = NEGBIG; l_[j] = 0.f; }
  f32x4 o0 = {0, 0, 0, 0}, o1 = {0, 0, 0, 0};

  const int ktmax = qt >> 1;
  int cur = 0;
  for (int kt = 0; kt <= ktmax; ++kt) {
    const int n0 = kt << 6;
    if (kt < ktmax) {
      STAGE_KV(kt + 1, cur ^ 1);
      vmwait<4>();
    } else {
      vmwait<0>();
    }
    __builtin_amdgcn_s_barrier();

    f32x4 s0 = {0, 0, 0, 0}, s1 = {0, 0, 0, 0};
#pragma unroll
    for (int ks = 0; ks < 2; ++ks) {
      const int kidx = ks * 4 + kh;
      bf16x8 a  = *(const bf16x8*)&Qs[kidx][wm + lr][0];
      bf16x8 b0 = *(const bf16x8*)&Ks[cur][kidx][wn + lr][0];
      bf16x8 b1 = *(const bf16x8*)&Ks[cur][kidx][wn + 16 + lr][0];
      s0 = MFMA(a, b0, s0); s1 = MFMA(a, b1, s1);
    }
    float pv0[4], pv1[4];
#pragma unroll
    for (int j = 0; j < 4; ++j) {
      const int grow = m0 + wm + (kh << 2) + j;
      float t0 = s0[j] * SCALEF; if (n0 + wn + lr > grow)      t0 = NEGBIG;
      float t1 = s1[j] * SCALEF; if (n0 + wn + 16 + lr > grow) t1 = NEGBIG;
      pv0[j] = t0; pv1[j] = t1;
      float v = fmaxf(t0, t1);
      v = fmaxf(v, __shfl_xor(v, 1)); v = fmaxf(v, __shfl_xor(v, 2));
      v = fmaxf(v, __shfl_xor(v, 4)); v = fmaxf(v, __shfl_xor(v, 8));
      wmaxp[(wave & 1) * 32 + wm + (kh << 2) + j] = v;
    }
    lgkm_barrier();

    float tmax[4]; bool need = false;
#pragma unroll
    for (int j = 0; j < 4; ++j) {
      const int rl = wm + (kh << 2) + j;
      tmax[j] = fmaxf(wmaxp[rl], wmaxp[32 + rl]);
      need |= (tmax[j] > m_[j] + 8.f);
    }
    if (__ballot(need)) {
#pragma unroll
      for (int j = 0; j < 4; ++j) {
        const float mn = fmaxf(m_[j], tmax[j]);
        const float al = __expf(m_[j] - mn);
        m_[j] = mn; l_[j] *= al; o0[j] *= al; o1[j] *= al;
      }
    }
#pragma unroll
    for (int j = 0; j < 4; ++j) {
      const float p0 = __expf(pv0[j] - m_[j]);
      const float p1 = __expf(pv1[j] - m_[j]);
      float rs = p0 + p1;
      rs += __shfl_xor(rs, 1); rs += __shfl_xor(rs, 2);
      rs += __shfl_xor(rs, 4); rs += __shfl_xor(rs, 8);
      const int rl = wm + (kh << 2) + j;
      wsump[(wave & 1) * 32 + rl] = rs;
      const int pc0 = wn + lr, pc1 = wn + 16 + lr;
      Ps[pc0 >> 3][rl][pc0 & 7] = (__bf16)p0;
      Ps[pc1 >> 3][rl][pc1 & 7] = (__bf16)p1;
    }
    lgkm_barrier();

#pragma unroll
    for (int j = 0; j < 4; ++j) {
      const int rl = wm + (kh << 2) + j;
      l_[j] += wsump[rl] + wsump[32 + rl];
    }
#pragma unroll
    for (int ks = 0; ks < 2; ++ks) {
      const int kidx = ks * 4 + kh;
      bf16x8 a  = *(const bf16x8*)&Ps[kidx][wm + lr][0];
      bf16x8 b0 = *(const bf16x8*)&Vs[cur][kidx][wn + lr][0];
      bf16x8 b1 = *(const bf16x8*)&Vs[cur][kidx][wn + 16 + lr][0];
      o0 = MFMA(a, b0, o0); o1 = MFMA(a, b1, o1);
    }
    __builtin_amdgcn_s_barrier();
    cur ^= 1;
  }

#pragma unroll
  for (int j = 0; j < 4; ++j) {
    const int row = m0 + wm + (kh << 2) + j;
    const float inv = 1.0f / l_[j];
    y2[((size_t)(b * TSEQ) + row) * EDIM + h * HDIM + wn + lr]      = (__bf16)(o0[j] * inv);
    y2[((size_t)(b * TSEQ) + row) * EDIM + h * HDIM + wn + 16 + lr] = (__bf16)(o1[j] * inv);
  }
}

// ---------------------------------------------------------------- launcher
extern "C" void kernel_launch(void* const* d_in, const int* in_sizes, int n_in,
                              void* d_out, int out_size, void* d_ws, size_t ws_size,
                              hipStream_t stream) {
  const int*   tokens  = (const int*)d_in[0];
  const float* emb     = (const float*)d_in[1];
  const float* Wqkv    = (const float*)d_in[2];
  const float* bqkv    = (const float*)d_in[3];
  const float* Wo      = (const float*)d_in[4];
  const float* bo      = (const float*)d_in[5];
  const float* W1      = (const float*)d_in[6];
  const float* b1      = (const float*)d_in[7];
  const float* W3      = (const float*)d_in[8];
  const float* b3      = (const float*)d_in[9];
  const float* W2w     = (const float*)d_in[10];
  const float* b2      = (const float*)d_in[11];
  const float* g_mha   = (const float*)d_in[12];
  const float* g_ff    = (const float*)d_in[13];
  const float* g_final = (const float*)d_in[14];
  const float* Wout    = (const float*)d_in[15];
  const float* bout    = (const float*)d_in[16];
  float* out = (float*)d_out;

  char* base = (char*)d_ws;
  size_t off = 0;
  auto alloc = [&](size_t bytes) { char* p = base + off; off = (off + bytes + 255) & ~(size_t)255; return p; };
  float*  x    = (float*)alloc(4u << 20);
  float*  part = (float*)alloc(2048);
  int*    cnt  = (int*)alloc(1024);
  __bf16* ybf  = (__bf16*)alloc(2u << 20);
  __bf16* qbf  = (__bf16*)alloc(2u << 20);
  __bf16* kbf  = (__bf16*)alloc(2u << 20);
  __bf16* vbT  = (__bf16*)alloc(2u << 20);
  __bf16* y2bf = (__bf16*)alloc(2u << 20);
  __bf16* ubf  = (__bf16*)alloc((size_t)MTOK * DPAD * 2);
  float*  pbuf = (float*)alloc((size_t)4 * NELEM * 4);
  __bf16* WoutT = (__bf16*)alloc((size_t)8192 * 1024 * 2);
  __bf16* qkvT = (__bf16*)alloc((size_t)NLAYER * 3072 * 1024 * 2);
  __bf16* woT  = (__bf16*)alloc((size_t)NLAYER * 1024 * 1024 * 2);
  __bf16* w1T  = (__bf16*)alloc((size_t)NLAYER * DPAD * 1024 * 2);
  __bf16* w3T  = (__bf16*)alloc((size_t)NLAYER * DPAD * 1024 * 2);
  __bf16* w2T  = (__bf16*)alloc((size_t)NLAYER * 1024 * DPAD * 2);

  ConvW cw;
  cw.Wqkv = Wqkv; cw.Wo = Wo; cw.W1 = W1; cw.W3 = W3; cw.W2w = W2w;
  cw.g_mha = g_mha; cw.g_ff = g_ff; cw.Wout = Wout; cw.g_final = g_final;
  cw.qkvT = qkvT; cw.woT = woT; cw.w1T = w1T; cw.w3T = w3T; cw.w2T = w2T;
  cw.WoutT = WoutT;

  hipMemsetAsync(cnt, 0, 1024, stream);                // split-K counters
  k_embed<<<MTOK, 256, 0, stream>>>(tokens, emb, x);
  k_conv0<<<LCONV, 256, 0, stream>>>(cw);              // layer-0 weights only
  k_red1f<<<256, 256, 0, stream>>>(x, part, ybf);

  for (int l = 0; l < NLAYER; ++l) {
    const int co = (l + 1 < NLAYER) ? (l + 1) * LCONV : ACONV;
    const int cn = (l + 1 < NLAYER) ? 772 : 512;
    const int pc = (l == 0) ? 256 : 128;
    // --- MHA ---
    mm<128, 0, 1><<<192 + cn, 256, 0, stream>>>(
        ybf, qkvT + (size_t)l * 3072 * 1024, nullptr,
        bqkv + (size_t)l * 3 * EDIM, nullptr, part, pc,
        nullptr, nullptr, qbf, kbf, vbT, nullptr, nullptr, nullptr,
        3072, 1024, 1024, 1024, 24, 8, 1, cw, co);
    k_flash<<<512 + cn, 256, 0, stream>>>(qbf, kbf, vbT, y2bf, cw, co + cn);
    // Wo split-K + fused fold: x += y2@Wo + bo; ybf; part[128]
    mm<64, 1, 0><<<512, 256, 0, stream>>>(
        y2bf, woT + (size_t)l * 1024 * 1024, nullptr,
        bo + (size_t)l * EDIM, nullptr, nullptr, 0,
        pbuf, ybf, nullptr, nullptr, nullptr, x, part, cnt,
        1024, 1024, 1024, 1024, 16, 8, 4, cw, 0);
    // --- SwiGLU FFN ---
    mm<64, 2, 1><<<344 + cn, 256, 0, stream>>>(
        ybf, w1T + (size_t)l * DPAD * 1024, w3T + (size_t)l * DPAD * 1024,
        b1 + (size_t)l * DFFDIM, b3 + (size_t)l * DFFDIM, part, 128,
        nullptr, ubf, nullptr, nullptr, nullptr, nullptr, nullptr, nullptr,
        DFFDIM, 1024, 1024, 1024, 43, 8, 1, cw, co + 2 * cn);
    // W2 split-K + fused fold: x += u@W2 + b2; ybf; part[128]
    mm<64, 1, 0><<<512 + cn, 256, 0, stream>>>(
        ubf, w2T + (size_t)l * 1024 * DPAD, nullptr,
        b2 + (size_t)l * EDIM, nullptr, nullptr, 0,
        pbuf, ybf, nullptr, nullptr, nullptr, x, part, cnt,
        1024, DPAD, DPAD, DPAD, 16, 8, 4, cw, co + 3 * cn);
  }

  // --- vocab head ---
  mm<128, 3, 1><<<512, 256, 0, stream>>>(
      ybf, WoutT, nullptr, bout, nullptr, part, 128,
      out, nullptr, nullptr, nullptr, nullptr, nullptr, nullptr, nullptr,
      VOCAB, 1024, 1024, 1024, 64, 8, 1, cw, 0);
}

// Round 17
// 3715.989 us; speedup vs baseline: 1.9730x; 1.9730x over previous
//
#include <hip/hip_runtime.h>
#include <hip/hip_bf16.h>
#include <math.h>

#define EDIM   1024
#define TSEQ   512
#define NBATCH 2
#define NHEAD  16
#define HDIM   64
#define NLAYER 24
#define VOCAB  8124
#define DFFDIM 2730
#define DPAD   2752              // 43*64 padded SwiGLU width
#define MTOK   (NBATCH*TSEQ)     // 1024
#define NELEM  (MTOK*EDIM)
#define EPSF   1e-5f
#define SCALEF (1.0f/32.0f)
#define NEGBIG (-1e30f)
#define LCONV  3088              // conv tiles per layer
#define ACONV  (NLAYER*LCONV)    // 74112, then head tiles follow
#define HCONV  2048

typedef __bf16 bf16x8 __attribute__((ext_vector_type(8)));
typedef __bf16 bf16x4 __attribute__((ext_vector_type(4)));
typedef float  f32x4  __attribute__((ext_vector_type(4)));

#define MFMA(a, b, c) __builtin_amdgcn_mfma_f32_16x16x32_bf16((a), (b), (c), 0, 0, 0)

__device__ __forceinline__ void gl_lds16(const __bf16* g, __bf16* l) {
  __builtin_amdgcn_global_load_lds(
      (const __attribute__((address_space(1))) void*)g,
      (__attribute__((address_space(3))) void*)l, 16, 0, 0);
}
template <int N> __device__ __forceinline__ void vmwait() {
  asm volatile("s_waitcnt vmcnt(%0)" :: "n"(N) : "memory");
}
__device__ __forceinline__ void lgkm_barrier() {
  asm volatile("s_waitcnt lgkmcnt(0)" ::: "memory");
  __builtin_amdgcn_s_barrier();
}

// ---------------- weight pointers bundle (for carrier conv blocks)
struct ConvW {
  const float *Wqkv, *Wo, *W1, *W3, *W2w, *g_mha, *g_ff, *Wout, *g_final;
  __bf16 *qkvT, *woT, *w1T, *w3T, *w2T, *WoutT;
};

// ---------------------------------------------------------------- embedding+PE
__global__ __launch_bounds__(256) void k_embed(const int* __restrict__ tok,
                                               const float* __restrict__ emb,
                                               float* __restrict__ x) {
  const int bt = blockIdx.x;
  const int t  = bt & (TSEQ - 1);
  const int tk = tok[bt];
  const float* er = emb + (size_t)tk * EDIM;
  float* xr = x + (size_t)bt * EDIM;
  for (int e = threadIdx.x * 4; e < EDIM; e += 256 * 4) {
    float4 v = *(const float4*)(er + e);
    float vv[4] = {v.x, v.y, v.z, v.w};
    float ou[4];
#pragma unroll
    for (int j = 0; j < 4; ++j) {
      int ee = e + j;
      int i2 = ee & ~1;
      float freq = expf(-(float)i2 * (9.210340371976184f / 1024.0f));
      float ang  = (float)t * freq;
      ou[j] = vv[j] + ((ee & 1) ? cosf(ang) : sinf(ang));
    }
    *(float4*)(xr + e) = make_float4(ou[0], ou[1], ou[2], ou[3]);
  }
}

// ----------------- RMS reduce (+fold 4 partials) + emit bf16(x)
__global__ __launch_bounds__(256) void k_red1f(float* __restrict__ x,
                                               const float* __restrict__ pb,
                                               int np,
                                               const float* __restrict__ bias,
                                               float* __restrict__ part,
                                               __bf16* __restrict__ ybf) {
  const int tid = threadIdx.x;
  float s = 0.f;
  const bool fold = (pb != nullptr);
  for (int i = (blockIdx.x * 256 + tid) * 4; i < NELEM; i += 256 * 256 * 4) {
    float4 v = *(const float4*)(x + i);
    if (fold) {
      for (int z = 0; z < np; ++z) {
        float4 a = *(const float4*)(pb + (size_t)z * NELEM + i);
        v.x += a.x; v.y += a.y; v.z += a.z; v.w += a.w;
      }
      float4 c = *(const float4*)(bias + (i & (EDIM - 1)));
      v.x += c.x; v.y += c.y; v.z += c.z; v.w += c.w;
      *(float4*)(x + i) = v;
    }
    bf16x4 o = {(__bf16)v.x, (__bf16)v.y, (__bf16)v.z, (__bf16)v.w};
    *(bf16x4*)(ybf + i) = o;
    s += v.x * v.x + v.y * v.y + v.z * v.z + v.w * v.w;
  }
#pragma unroll
  for (int o = 32; o > 0; o >>= 1) s += __shfl_down(s, o);
  __shared__ float sm[4];
  if ((tid & 63) == 0) sm[tid >> 6] = s;
  __syncthreads();
  if (tid == 0) part[blockIdx.x] = sm[0] + sm[1] + sm[2] + sm[3];
}

// ------------------------------------------------- weight convert + transpose
__device__ void conv_tile(const float* __restrict__ src,
                          const float* __restrict__ gk,
                          __bf16* __restrict__ dst,
                          int K, int N, int Kpad, int tk, int tn, char* smv) {
  float (*st)[65] = (float (*)[65])smv;   // 64 x 65 f32 = 16,640 B
  const int k0 = tk << 6, n0 = tn << 6;
  const int tid = threadIdx.x;
  {
    const int r0 = tid >> 4, c4 = (tid & 15) << 2;
#pragma unroll
    for (int i = 0; i < 4; ++i) {
      const int r = r0 + i * 16;
      const int k = k0 + r;
      f32x4 v = {0.f, 0.f, 0.f, 0.f};
      if (k < K) {
        const float* sp = src + (size_t)k * N + n0 + c4;
        if (n0 + c4 + 3 < N) v = __builtin_nontemporal_load((const f32x4*)sp);
        else {
          if (n0 + c4 + 0 < N) v[0] = sp[0];
          if (n0 + c4 + 1 < N) v[1] = sp[1];
          if (n0 + c4 + 2 < N) v[2] = sp[2];
          if (n0 + c4 + 3 < N) v[3] = sp[3];
        }
        if (gk) {
          const float gv = gk[k];
          v[0] *= gv; v[1] *= gv; v[2] *= gv; v[3] *= gv;
        }
      }
      st[r][c4 + 0] = v[0]; st[r][c4 + 1] = v[1];
      st[r][c4 + 2] = v[2]; st[r][c4 + 3] = v[3];
    }
  }
  __syncthreads();
  {
    const int nl0 = tid >> 3, c8 = (tid & 7) << 3;
#pragma unroll
    for (int i = 0; i < 2; ++i) {
      const int nl = nl0 + i * 32;
      bf16x8 o = {(__bf16)st[c8 + 0][nl], (__bf16)st[c8 + 1][nl],
                  (__bf16)st[c8 + 2][nl], (__bf16)st[c8 + 3][nl],
                  (__bf16)st[c8 + 4][nl], (__bf16)st[c8 + 5][nl],
                  (__bf16)st[c8 + 6][nl], (__bf16)st[c8 + 7][nl]};
      *(bf16x8*)&dst[(size_t)(n0 + nl) * Kpad + k0 + c8] = o;
    }
  }
}

// global conv tile space: [0, ACONV) layer tiles; [ACONV, ACONV+HCONV) head.
__device__ void conv_dispatch(int g, const ConvW& cw, char* sm) {
  if (g < ACONV) {
    const int l = g / LCONV;
    int b = g - l * LCONV;
    if (b < 768) {
      conv_tile(cw.Wqkv + (size_t)l * 1024 * 3072, cw.g_mha + (size_t)l * EDIM,
                cw.qkvT + (size_t)l * 3072 * 1024, 1024, 3072, 1024,
                b / 48, b % 48, sm);
    } else if (b < 1024) {
      int t = b - 768;
      conv_tile(cw.Wo + (size_t)l * 1024 * 1024, nullptr,
                cw.woT + (size_t)l * 1024 * 1024, 1024, 1024, 1024,
                t / 16, t % 16, sm);
    } else if (b < 1712) {
      int t = b - 1024;
      conv_tile(cw.W1 + (size_t)l * 1024 * DFFDIM, cw.g_ff + (size_t)l * EDIM,
                cw.w1T + (size_t)l * DPAD * 1024, 1024, DFFDIM, 1024,
                t / 43, t % 43, sm);
    } else if (b < 2400) {
      int t = b - 1712;
      conv_tile(cw.W3 + (size_t)l * 1024 * DFFDIM, cw.g_ff + (size_t)l * EDIM,
                cw.w3T + (size_t)l * DPAD * 1024, 1024, DFFDIM, 1024,
                t / 43, t % 43, sm);
    } else {
      int t = b - 2400;
      conv_tile(cw.W2w + (size_t)l * DFFDIM * 1024, nullptr,
                cw.w2T + (size_t)l * 1024 * DPAD, DFFDIM, 1024, DPAD,
                t / 16, t % 16, sm);
    }
  } else {
    const int t = g - ACONV;
    conv_tile(cw.Wout, cw.g_final, cw.WoutT, 1024, VOCAB, 1024,
              t >> 7, t & 127, sm);
  }
}

__global__ __launch_bounds__(256) void k_conv0(ConvW cw) {
  __shared__ __align__(16) char sm[16640];
  conv_dispatch(blockIdx.x, cw, sm);
}

// ================================================================ MFMA GEMM
// BM=128, BN in {64,128}; BK=64; 4 waves, wave tile 64 x BN/2.
// A/B bf16 via global_load_lds, counted-vmcnt double buffer. Flattened 1D
// grid; blocks past nx*ny*gz run carrier conv tiles.
// MODE: 0=qkv scatter  1=split-K f32 partial  2=SwiGLU dual  3=head
template <int BN, int MODE, int SC>
__global__ __launch_bounds__(256) void mm(
    const __bf16* __restrict__ A,
    const __bf16* __restrict__ B0w, const __bf16* __restrict__ B1w,
    const float* __restrict__ bias0, const float* __restrict__ bias1,
    const float* __restrict__ part,
    float* __restrict__ po, __bf16* __restrict__ ob,
    __bf16* __restrict__ qout, __bf16* __restrict__ kout, __bf16* __restrict__ vout,
    int N, int lda, int ldb, int Ktot,
    int nx, int ny, int gz, ConvW cw, int convoff) {
  constexpr int DUAL = (MODE == 2) ? 2 : 1;
  constexpr int FN = BN / 32;
  constexpr int BL = (BN == 128) ? 4 : 2 * DUAL;
  constexpr int ASZ = 32768;                 // [2][8][128][8] bf16
  constexpr int BSZ = DUAL * BN * 256;       // [2][DUAL][8][BN][8] bf16
  __shared__ __align__(16) char smem[ASZ + BSZ];
  const int bid = blockIdx.x;
  const int ncomp = nx * ny * gz;
  if (bid >= ncomp) {
    conv_dispatch(convoff + (bid - ncomp), cw, smem);
    return;
  }
  typedef __bf16 (*AsP)[8][128][8];
  typedef __bf16 (*BsP)[DUAL][8][BN][8];
  AsP As = (AsP)smem;
  BsP Bs = (BsP)(smem + ASZ);
  const int bz = bid / (nx * ny);
  const int r2 = bid - bz * nx * ny;
  const int by = r2 / nx, bx = r2 - by * nx;
  const int tid = threadIdx.x, lane = tid & 63, wave = tid >> 6;
  const int m0 = by << 7, n0 = bx * BN;
  const int wm0 = (wave >> 1) * 64, wn0 = (wave & 1) * (BN / 2);
  const int lr = lane & 15, kh = lane >> 4;

  const int ktiles = Ktot >> 6;
  const int nt0 = (ktiles + gz - 1) / gz;
  const int tbeg = bz * nt0;
  const int tend = (ktiles < tbeg + nt0) ? ktiles : (tbeg + nt0);
  const int nt = tend - tbeg;

  f32x4 acc[DUAL][4][FN];
#pragma unroll
  for (int d = 0; d < DUAL; ++d)
#pragma unroll
    for (int mi = 0; mi < 4; ++mi)
#pragma unroll
      for (int fn = 0; fn < FN; ++fn) acc[d][mi][fn] = (f32x4){0.f, 0.f, 0.f, 0.f};

  auto STAGE = [&](int buf, int t) {
    const int k0 = (tbeg + t) << 6;
#pragma unroll
    for (int i = 0; i < 4; ++i) {
      const int d = i * 256 + tid;
      gl_lds16(A + (size_t)(m0 + (d & 127)) * lda + k0 + (d >> 7) * 8,
               &As[buf][d >> 7][d & 127][0]);
    }
    if (BN == 128) {
#pragma unroll
      for (int i = 0; i < 4; ++i) {
        const int d = i * 256 + tid;
        gl_lds16(B0w + (size_t)(n0 + (d & 127)) * ldb + k0 + (d >> 7) * 8,
                 &Bs[buf][0][d >> 7][d & 127][0]);
      }
    } else {
#pragma unroll
      for (int i = 0; i < 2; ++i) {
        const int d = i * 256 + tid;
        gl_lds16(B0w + (size_t)(n0 + (d & 63)) * ldb + k0 + (d >> 6) * 8,
                 &Bs[buf][0][d >> 6][d & 63][0]);
      }
      if (DUAL == 2) {
#pragma unroll
        for (int i = 0; i < 2; ++i) {
          const int d = i * 256 + tid;
          gl_lds16(B1w + (size_t)(n0 + (d & 63)) * ldb + k0 + (d >> 6) * 8,
                   &Bs[buf][DUAL - 1][d >> 6][d & 63][0]);
        }
      }
    }
  };
  auto COMP = [&](int buf) {
#pragma unroll
    for (int ks = 0; ks < 2; ++ks) {
      const int kidx = ks * 4 + kh;
      bf16x8 af[4];
#pragma unroll
      for (int mi = 0; mi < 4; ++mi)
        af[mi] = *(const bf16x8*)&As[buf][kidx][wm0 + mi * 16 + lr][0];
#pragma unroll
      for (int d = 0; d < DUAL; ++d)
#pragma unroll
        for (int fn = 0; fn < FN; ++fn) {
          bf16x8 bfr = *(const bf16x8*)&Bs[buf][d][kidx][wn0 + fn * 16 + lr][0];
#pragma unroll
          for (int mi = 0; mi < 4; ++mi)
            acc[d][mi][fn] = MFMA(af[mi], bfr, acc[d][mi][fn]);
        }
    }
  };

  STAGE(0, 0);
  int cur = 0;
  for (int t = 0; t < nt - 1; ++t) {
    STAGE(cur ^ 1, t + 1);          // next tile stays in flight
    vmwait<4 + BL>();               // own tile-t loads retired
    __builtin_amdgcn_s_barrier();
    COMP(cur);
    __builtin_amdgcn_s_barrier();
    cur ^= 1;
  }
  vmwait<0>();
  __builtin_amdgcn_s_barrier();
  COMP(cur);

  float sc = 1.0f;
  if (SC) {
    __shared__ float smr[4];
    float s = part[tid];
#pragma unroll
    for (int o = 32; o > 0; o >>= 1) s += __shfl_down(s, o);
    if ((tid & 63) == 0) smr[tid >> 6] = s;
    __syncthreads();
    sc = 1.0f / sqrtf((smr[0] + smr[1] + smr[2] + smr[3]) / (float)NELEM + EPSF);
  }

#pragma unroll
  for (int mi = 0; mi < 4; ++mi)
#pragma unroll
    for (int fn = 0; fn < FN; ++fn) {
      const int col = n0 + wn0 + fn * 16 + lr;
      if (MODE == 0) {
        const float bs = bias0[col];
        const int h = col / (3 * HDIM);
        const int rsel = (col >> 6) % 3;
        const int s2 = col & (HDIM - 1);
#pragma unroll
        for (int j = 0; j < 4; ++j) {
          const int row = m0 + wm0 + mi * 16 + (kh << 2) + j;
          const int b = row >> 9, t = row & (TSEQ - 1);
          const float v = acc[0][mi][fn][j] * sc + bs;
          if (rsel == 0)      qout[((size_t)(b * NHEAD + h) * TSEQ + t) * HDIM + s2] = (__bf16)v;
          else if (rsel == 1) kout[((size_t)(b * NHEAD + h) * TSEQ + t) * HDIM + s2] = (__bf16)v;
          else                vout[((size_t)(b * NHEAD + h) * HDIM + s2) * TSEQ + t] = (__bf16)v;
        }
      } else if (MODE == 1) {
        float* pz = po + (size_t)bz * NELEM;
#pragma unroll
        for (int j = 0; j < 4; ++j) {
          const int row = m0 + wm0 + mi * 16 + (kh << 2) + j;
          pz[(size_t)row * EDIM + col] = acc[0][mi][fn][j];
        }
      } else if (MODE == 2) {
        const bool ok = col < N;
        const float bb1 = ok ? bias0[col] : 0.f;
        const float bb3 = ok ? bias1[col] : 0.f;
#pragma unroll
        for (int j = 0; j < 4; ++j) {
          const int row = m0 + wm0 + mi * 16 + (kh << 2) + j;
          float v = 0.f;
          if (ok) {
            const float a1v = acc[0][mi][fn][j] * sc + bb1;
            const float a3v = acc[DUAL - 1][mi][fn][j] * sc + bb3;
            v = a1v * (1.0f / (1.0f + __expf(-a1v))) * a3v;
          }
          ob[(size_t)row * DPAD + col] = (__bf16)v;
        }
      } else {
        if (col < N) {
          const float bs = bias0[col];
#pragma unroll
          for (int j = 0; j < 4; ++j) {
            const int row = m0 + wm0 + mi * 16 + (kh << 2) + j;
            po[(size_t)row * N + col] = acc[0][mi][fn][j] * sc + bs;
          }
        }
      }
    }
}

// ------------------------------------------------- flash attention (bf16 in)
// 32-row Q tiles; 512 compute blocks + carrier conv blocks. dbuf K/V,
// counted vmcnt, defer-max THR=8.
__global__ __launch_bounds__(256) void k_flash(const __bf16* __restrict__ qbuf,
                                               const __bf16* __restrict__ kbuf,
                                               const __bf16* __restrict__ vbufT,
                                               __bf16* __restrict__ y2,
                                               ConvW cw, int convoff) {
  __shared__ __align__(16) char smem[41472];
  const int bid = blockIdx.x;
  if (bid >= 512) {
    conv_dispatch(convoff + (bid - 512), cw, smem);
    return;
  }
  const int qt = bid & 15, bh = bid >> 4;
  const int b = bh >> 4, h = bh & 15;
  const int m0 = qt << 5;
  const __bf16* qp = qbuf  + (size_t)bh * TSEQ * HDIM;
  const __bf16* kp = kbuf  + (size_t)bh * TSEQ * HDIM;
  const __bf16* vp = vbufT + (size_t)bh * HDIM * TSEQ;   // [d][t]
  __bf16 (*Qs)[32][8]    = (__bf16 (*)[32][8])smem;                    // 4KB
  __bf16 (*Ks)[8][64][8] = (__bf16 (*)[8][64][8])(smem + 4096);        // 16KB
  __bf16 (*Vs)[8][64][8] = (__bf16 (*)[8][64][8])(smem + 20480);       // 16KB
  __bf16 (*Ps)[32][8]    = (__bf16 (*)[32][8])(smem + 36864);          // 4KB
  float* wmaxp = (float*)(smem + 40960);                               // [2][32]
  float* wsump = wmaxp + 64;                                           // [2][32]
  const int tid = threadIdx.x, lane = tid & 63, wave = tid >> 6;
  const int wm = (wave >> 1) << 4, wn = (wave & 1) << 5;
  const int lr = lane & 15, kh = lane >> 4;

  auto STAGE_KV = [&](int kt2, int buf) {
    const int n0s = kt2 << 6;
#pragma unroll
    for (int i = 0; i < 2; ++i) {
      const int d = i * 256 + tid;
      const int kb2 = d >> 6, row = d & 63;
      gl_lds16(kp + (size_t)(n0s + row) * HDIM + kb2 * 8, &Ks[buf][kb2][row][0]);
      gl_lds16(vp + (size_t)row * TSEQ + n0s + kb2 * 8, &Vs[buf][kb2][row][0]);
    }
  };

  gl_lds16(qp + (size_t)(m0 + (tid & 31)) * HDIM + (tid >> 5) * 8,
           &Qs[tid >> 5][tid & 31][0]);
  STAGE_KV(0, 0);

  float m_[4], l_[4];
#pragma unroll
  for (int j = 0; j < 4; ++j) { m_[j] = NEGBIG; l_[j] = 0.f; }
  f32x4 o0 = {0, 0, 0, 0}, o1 = {0, 0, 0, 0};

  const int ktmax = qt >> 1;
  int cur = 0;
  for (int kt = 0; kt <= ktmax; ++kt) {
    const int n0 = kt << 6;
    if (kt < ktmax) {
      STAGE_KV(kt + 1, cur ^ 1);
      vmwait<4>();
    } else {
      vmwait<0>();
    }
    __builtin_amdgcn_s_barrier();

    f32x4 s0 = {0, 0, 0, 0}, s1 = {0, 0, 0, 0};
#pragma unroll
    for (int ks = 0; ks < 2; ++ks) {
      const int kidx = ks * 4 + kh;
      bf16x8 a  = *(const bf16x8*)&Qs[kidx][wm + lr][0];
      bf16x8 b0 = *(const bf16x8*)&Ks[cur][kidx][wn + lr][0];
      bf16x8 b1 = *(const bf16x8*)&Ks[cur][kidx][wn + 16 + lr][0];
      s0 = MFMA(a, b0, s0); s1 = MFMA(a, b1, s1);
    }
    float pv0[4], pv1[4];
#pragma unroll
    for (int j = 0; j < 4; ++j) {
      const int grow = m0 + wm + (kh << 2) + j;
      float t0 = s0[j] * SCALEF; if (n0 + wn + lr > grow)      t0 = NEGBIG;
      float t1 = s1[j] * SCALEF; if (n0 + wn + 16 + lr > grow) t1 = NEGBIG;
      pv0[j] = t0; pv1[j] = t1;
      float v = fmaxf(t0, t1);
      v = fmaxf(v, __shfl_xor(v, 1)); v = fmaxf(v, __shfl_xor(v, 2));
      v = fmaxf(v, __shfl_xor(v, 4)); v = fmaxf(v, __shfl_xor(v, 8));
      wmaxp[(wave & 1) * 32 + wm + (kh << 2) + j] = v;
    }
    lgkm_barrier();

    float tmax[4]; bool need = false;
#pragma unroll
    for (int j = 0; j < 4; ++j) {
      const int rl = wm + (kh << 2) + j;
      tmax[j] = fmaxf(wmaxp[rl], wmaxp[32 + rl]);
      need |= (tmax[j] > m_[j] + 8.f);
    }
    if (__ballot(need)) {
#pragma unroll
      for (int j = 0; j < 4; ++j) {
        const float mn = fmaxf(m_[j], tmax[j]);
        const float al = __expf(m_[j] - mn);
        m_[j] = mn; l_[j] *= al; o0[j] *= al; o1[j] *= al;
      }
    }
#pragma unroll
    for (int j = 0; j < 4; ++j) {
      const float p0 = __expf(pv0[j] - m_[j]);
      const float p1 = __expf(pv1[j] - m_[j]);
      float rs = p0 + p1;
      rs += __shfl_xor(rs, 1); rs += __shfl_xor(rs, 2);
      rs += __shfl_xor(rs, 4); rs += __shfl_xor(rs, 8);
      const int rl = wm + (kh << 2) + j;
      wsump[(wave & 1) * 32 + rl] = rs;
      const int pc0 = wn + lr, pc1 = wn + 16 + lr;
      Ps[pc0 >> 3][rl][pc0 & 7] = (__bf16)p0;
      Ps[pc1 >> 3][rl][pc1 & 7] = (__bf16)p1;
    }
    lgkm_barrier();

#pragma unroll
    for (int j = 0; j < 4; ++j) {
      const int rl = wm + (kh << 2) + j;
      l_[j] += wsump[rl] + wsump[32 + rl];
    }
#pragma unroll
    for (int ks = 0; ks < 2; ++ks) {
      const int kidx = ks * 4 + kh;
      bf16x8 a  = *(const bf16x8*)&Ps[kidx][wm + lr][0];
      bf16x8 b0 = *(const bf16x8*)&Vs[cur][kidx][wn + lr][0];
      bf16x8 b1 = *(const bf16x8*)&Vs[cur][kidx][wn + 16 + lr][0];
      o0 = MFMA(a, b0, o0); o1 = MFMA(a, b1, o1);
    }
    __builtin_amdgcn_s_barrier();
    cur ^= 1;
  }

#pragma unroll
  for (int j = 0; j < 4; ++j) {
    const int row = m0 + wm + (kh << 2) + j;
    const float inv = 1.0f / l_[j];
    y2[((size_t)(b * TSEQ) + row) * EDIM + h * HDIM + wn + lr]      = (__bf16)(o0[j] * inv);
    y2[((size_t)(b * TSEQ) + row) * EDIM + h * HDIM + wn + 16 + lr] = (__bf16)(o1[j] * inv);
  }
}

// ---------------------------------------------------------------- launcher
extern "C" void kernel_launch(void* const* d_in, const int* in_sizes, int n_in,
                              void* d_out, int out_size, void* d_ws, size_t ws_size,
                              hipStream_t stream) {
  const int*   tokens  = (const int*)d_in[0];
  const float* emb     = (const float*)d_in[1];
  const float* Wqkv    = (const float*)d_in[2];
  const float* bqkv    = (const float*)d_in[3];
  const float* Wo      = (const float*)d_in[4];
  const float* bo      = (const float*)d_in[5];
  const float* W1      = (const float*)d_in[6];
  const float* b1      = (const float*)d_in[7];
  const float* W3      = (const float*)d_in[8];
  const float* b3      = (const float*)d_in[9];
  const float* W2w     = (const float*)d_in[10];
  const float* b2      = (const float*)d_in[11];
  const float* g_mha   = (const float*)d_in[12];
  const float* g_ff    = (const float*)d_in[13];
  const float* g_final = (const float*)d_in[14];
  const float* Wout    = (const float*)d_in[15];
  const float* bout    = (const float*)d_in[16];
  float* out = (float*)d_out;

  char* base = (char*)d_ws;
  size_t off = 0;
  auto alloc = [&](size_t bytes) { char* p = base + off; off = (off + bytes + 255) & ~(size_t)255; return p; };
  float*  x    = (float*)alloc(4u << 20);
  float*  part = (float*)alloc(2048);
  __bf16* ybf  = (__bf16*)alloc(2u << 20);
  __bf16* qbf  = (__bf16*)alloc(2u << 20);
  __bf16* kbf  = (__bf16*)alloc(2u << 20);
  __bf16* vbT  = (__bf16*)alloc(2u << 20);
  __bf16* y2bf = (__bf16*)alloc(2u << 20);
  __bf16* ubf  = (__bf16*)alloc((size_t)MTOK * DPAD * 2);
  float*  pbuf = (float*)alloc((size_t)4 * NELEM * 4);
  __bf16* WoutT = (__bf16*)alloc((size_t)8192 * 1024 * 2);
  __bf16* qkvT = (__bf16*)alloc((size_t)NLAYER * 3072 * 1024 * 2);
  __bf16* woT  = (__bf16*)alloc((size_t)NLAYER * 1024 * 1024 * 2);
  __bf16* w1T  = (__bf16*)alloc((size_t)NLAYER * DPAD * 1024 * 2);
  __bf16* w3T  = (__bf16*)alloc((size_t)NLAYER * DPAD * 1024 * 2);
  __bf16* w2T  = (__bf16*)alloc((size_t)NLAYER * 1024 * DPAD * 2);

  ConvW cw;
  cw.Wqkv = Wqkv; cw.Wo = Wo; cw.W1 = W1; cw.W3 = W3; cw.W2w = W2w;
  cw.g_mha = g_mha; cw.g_ff = g_ff; cw.Wout = Wout; cw.g_final = g_final;
  cw.qkvT = qkvT; cw.woT = woT; cw.w1T = w1T; cw.w3T = w3T; cw.w2T = w2T;
  cw.WoutT = WoutT;

  k_embed<<<MTOK, 256, 0, stream>>>(tokens, emb, x);
  k_conv0<<<LCONV, 256, 0, stream>>>(cw);              // layer-0 weights only
  k_red1f<<<256, 256, 0, stream>>>(x, nullptr, 0, nullptr, part, ybf);

  const float* pend_bias = nullptr;
  for (int l = 0; l < NLAYER; ++l) {
    // carriers convert layer l+1 (or the head when l==23)
    const int co = (l + 1 < NLAYER) ? (l + 1) * LCONV : ACONV;
    const int cn = (l + 1 < NLAYER) ? 772 : 512;       // 4 carrier groups/layer
    // --- MHA ---  (QKV at 128x128 tiles: 192 compute blocks + carriers)
    mm<128, 0, 1><<<192 + cn, 256, 0, stream>>>(
        ybf, qkvT + (size_t)l * 3072 * 1024, nullptr,
        bqkv + (size_t)l * 3 * EDIM, nullptr, part,
        nullptr, nullptr, qbf, kbf, vbT, 3072, 1024, 1024, 1024,
        24, 8, 1, cw, co);
    k_flash<<<512 + cn, 256, 0, stream>>>(qbf, kbf, vbT, y2bf, cw, co + cn);
    mm<64, 1, 0><<<512, 256, 0, stream>>>(
        y2bf, woT + (size_t)l * 1024 * 1024, nullptr,
        nullptr, nullptr, nullptr,
        pbuf, nullptr, nullptr, nullptr, nullptr, 1024, 1024, 1024, 1024,
        16, 8, 4, cw, 0);
    // --- SwiGLU FFN ---
    k_red1f<<<256, 256, 0, stream>>>(x, pbuf, 4, bo + (size_t)l * EDIM, part, ybf);
    mm<64, 2, 1><<<344 + cn, 256, 0, stream>>>(
        ybf, w1T + (size_t)l * DPAD * 1024, w3T + (size_t)l * DPAD * 1024,
        b1 + (size_t)l * DFFDIM, b3 + (size_t)l * DFFDIM, part,
        nullptr, ubf, nullptr, nullptr, nullptr, DFFDIM, 1024, 1024, 1024,
        43, 8, 1, cw, co + 2 * cn);
    mm<64, 1, 0><<<512 + cn, 256, 0, stream>>>(
        ubf, w2T + (size_t)l * 1024 * DPAD, nullptr,
        nullptr, nullptr, nullptr,
        pbuf, nullptr, nullptr, nullptr, nullptr, 1024, DPAD, DPAD, DPAD,
        16, 8, 4, cw, co + 3 * cn);
    pend_bias = b2 + (size_t)l * EDIM;
    // fold w2 partials + b2; emits next layer's (or head's) ybf/part
    k_red1f<<<256, 256, 0, stream>>>(x, pbuf, 4, pend_bias, part, ybf);
  }

  // --- vocab head ---
  mm<128, 3, 1><<<512, 256, 0, stream>>>(
      ybf, WoutT, nullptr, bout, nullptr, part,
      out, nullptr, nullptr, nullptr, nullptr, VOCAB, 1024, 1024, 1024,
      64, 8, 1, cw, 0);
}

// Round 18
// 3636.548 us; speedup vs baseline: 2.0161x; 1.0218x over previous
//
#include <hip/hip_runtime.h>
#include <hip/hip_bf16.h>
#include <math.h>

#define EDIM   1024
#define TSEQ   512
#define NBATCH 2
#define NHEAD  16
#define HDIM   64
#define NLAYER 24
#define VOCAB  8124
#define DFFDIM 2730
#define DPAD   2752              // 43*64 padded SwiGLU width
#define MTOK   (NBATCH*TSEQ)     // 1024
#define NELEM  (MTOK*EDIM)
#define EPSF   1e-5f
#define SCALEF (1.0f/32.0f)
#define NEGBIG (-1e30f)
#define LCONV  3088              // conv tiles per layer
#define ACONV  (NLAYER*LCONV)    // 74112, then head tiles follow
#define HCONV  2048

typedef __bf16 bf16x8 __attribute__((ext_vector_type(8)));
typedef __bf16 bf16x4 __attribute__((ext_vector_type(4)));
typedef float  f32x4  __attribute__((ext_vector_type(4)));

#define MFMA(a, b, c) __builtin_amdgcn_mfma_f32_16x16x32_bf16((a), (b), (c), 0, 0, 0)

__device__ __forceinline__ void gl_lds16(const __bf16* g, __bf16* l) {
  __builtin_amdgcn_global_load_lds(
      (const __attribute__((address_space(1))) void*)g,
      (__attribute__((address_space(3))) void*)l, 16, 0, 0);
}
template <int N> __device__ __forceinline__ void vmwait() {
  asm volatile("s_waitcnt vmcnt(%0)" :: "n"(N) : "memory");
}
__device__ __forceinline__ void lgkm_barrier() {
  asm volatile("s_waitcnt lgkmcnt(0)" ::: "memory");
  __builtin_amdgcn_s_barrier();
}

// ---------------- weight pointers bundle (for carrier conv blocks)
struct ConvW {
  const float *Wqkv, *Wo, *W1, *W3, *W2w, *g_mha, *g_ff, *Wout, *g_final;
  __bf16 *qkvT, *woT, *w1T, *w3T, *w2T, *WoutT;
};

// ---------------------------------------------------------------- embedding+PE
__global__ __launch_bounds__(256) void k_embed(const int* __restrict__ tok,
                                               const float* __restrict__ emb,
                                               float* __restrict__ x) {
  const int bt = blockIdx.x;
  const int t  = bt & (TSEQ - 1);
  const int tk = tok[bt];
  const float* er = emb + (size_t)tk * EDIM;
  float* xr = x + (size_t)bt * EDIM;
  for (int e = threadIdx.x * 4; e < EDIM; e += 256 * 4) {
    float4 v = *(const float4*)(er + e);
    float vv[4] = {v.x, v.y, v.z, v.w};
    float ou[4];
#pragma unroll
    for (int j = 0; j < 4; ++j) {
      int ee = e + j;
      int i2 = ee & ~1;
      float freq = expf(-(float)i2 * (9.210340371976184f / 1024.0f));
      float ang  = (float)t * freq;
      ou[j] = vv[j] + ((ee & 1) ? cosf(ang) : sinf(ang));
    }
    *(float4*)(xr + e) = make_float4(ou[0], ou[1], ou[2], ou[3]);
  }
}

// ----------------- RMS reduce (+fold 4 partials) + emit bf16(x)
__global__ __launch_bounds__(256) void k_red1f(float* __restrict__ x,
                                               const float* __restrict__ pb,
                                               int np,
                                               const float* __restrict__ bias,
                                               float* __restrict__ part,
                                               __bf16* __restrict__ ybf) {
  const int tid = threadIdx.x;
  float s = 0.f;
  const bool fold = (pb != nullptr);
  for (int i = (blockIdx.x * 256 + tid) * 4; i < NELEM; i += 256 * 256 * 4) {
    float4 v = *(const float4*)(x + i);
    if (fold) {
      for (int z = 0; z < np; ++z) {
        float4 a = *(const float4*)(pb + (size_t)z * NELEM + i);
        v.x += a.x; v.y += a.y; v.z += a.z; v.w += a.w;
      }
      float4 c = *(const float4*)(bias + (i & (EDIM - 1)));
      v.x += c.x; v.y += c.y; v.z += c.z; v.w += c.w;
      *(float4*)(x + i) = v;
    }
    bf16x4 o = {(__bf16)v.x, (__bf16)v.y, (__bf16)v.z, (__bf16)v.w};
    *(bf16x4*)(ybf + i) = o;
    s += v.x * v.x + v.y * v.y + v.z * v.z + v.w * v.w;
  }
#pragma unroll
  for (int o = 32; o > 0; o >>= 1) s += __shfl_down(s, o);
  __shared__ float sm[4];
  if ((tid & 63) == 0) sm[tid >> 6] = s;
  __syncthreads();
  if (tid == 0) part[blockIdx.x] = sm[0] + sm[1] + sm[2] + sm[3];
}

// ------------------------------------------------- weight convert + transpose
__device__ void conv_tile(const float* __restrict__ src,
                          const float* __restrict__ gk,
                          __bf16* __restrict__ dst,
                          int K, int N, int Kpad, int tk, int tn, char* smv) {
  float (*st)[65] = (float (*)[65])smv;   // 64 x 65 f32 = 16,640 B
  const int k0 = tk << 6, n0 = tn << 6;
  const int tid = threadIdx.x;
  {
    const int r0 = tid >> 4, c4 = (tid & 15) << 2;
#pragma unroll
    for (int i = 0; i < 4; ++i) {
      const int r = r0 + i * 16;
      const int k = k0 + r;
      f32x4 v = {0.f, 0.f, 0.f, 0.f};
      if (k < K) {
        const float* sp = src + (size_t)k * N + n0 + c4;
        if (n0 + c4 + 3 < N) v = __builtin_nontemporal_load((const f32x4*)sp);
        else {
          if (n0 + c4 + 0 < N) v[0] = sp[0];
          if (n0 + c4 + 1 < N) v[1] = sp[1];
          if (n0 + c4 + 2 < N) v[2] = sp[2];
          if (n0 + c4 + 3 < N) v[3] = sp[3];
        }
        if (gk) {
          const float gv = gk[k];
          v[0] *= gv; v[1] *= gv; v[2] *= gv; v[3] *= gv;
        }
      }
      st[r][c4 + 0] = v[0]; st[r][c4 + 1] = v[1];
      st[r][c4 + 2] = v[2]; st[r][c4 + 3] = v[3];
    }
  }
  __syncthreads();
  {
    const int nl0 = tid >> 3, c8 = (tid & 7) << 3;
#pragma unroll
    for (int i = 0; i < 2; ++i) {
      const int nl = nl0 + i * 32;
      bf16x8 o = {(__bf16)st[c8 + 0][nl], (__bf16)st[c8 + 1][nl],
                  (__bf16)st[c8 + 2][nl], (__bf16)st[c8 + 3][nl],
                  (__bf16)st[c8 + 4][nl], (__bf16)st[c8 + 5][nl],
                  (__bf16)st[c8 + 6][nl], (__bf16)st[c8 + 7][nl]};
      *(bf16x8*)&dst[(size_t)(n0 + nl) * Kpad + k0 + c8] = o;
    }
  }
}

// global conv tile space: [0, ACONV) layer tiles; [ACONV, ACONV+HCONV) head.
__device__ void conv_dispatch(int g, const ConvW& cw, char* sm) {
  if (g < ACONV) {
    const int l = g / LCONV;
    int b = g - l * LCONV;
    if (b < 768) {
      conv_tile(cw.Wqkv + (size_t)l * 1024 * 3072, cw.g_mha + (size_t)l * EDIM,
                cw.qkvT + (size_t)l * 3072 * 1024, 1024, 3072, 1024,
                b / 48, b % 48, sm);
    } else if (b < 1024) {
      int t = b - 768;
      conv_tile(cw.Wo + (size_t)l * 1024 * 1024, nullptr,
                cw.woT + (size_t)l * 1024 * 1024, 1024, 1024, 1024,
                t / 16, t % 16, sm);
    } else if (b < 1712) {
      int t = b - 1024;
      conv_tile(cw.W1 + (size_t)l * 1024 * DFFDIM, cw.g_ff + (size_t)l * EDIM,
                cw.w1T + (size_t)l * DPAD * 1024, 1024, DFFDIM, 1024,
                t / 43, t % 43, sm);
    } else if (b < 2400) {
      int t = b - 1712;
      conv_tile(cw.W3 + (size_t)l * 1024 * DFFDIM, cw.g_ff + (size_t)l * EDIM,
                cw.w3T + (size_t)l * DPAD * 1024, 1024, DFFDIM, 1024,
                t / 43, t % 43, sm);
    } else {
      int t = b - 2400;
      conv_tile(cw.W2w + (size_t)l * DFFDIM * 1024, nullptr,
                cw.w2T + (size_t)l * 1024 * DPAD, DFFDIM, 1024, DPAD,
                t / 16, t % 16, sm);
    }
  } else {
    const int t = g - ACONV;
    conv_tile(cw.Wout, cw.g_final, cw.WoutT, 1024, VOCAB, 1024,
              t >> 7, t & 127, sm);
  }
}

__global__ __launch_bounds__(256) void k_conv0(ConvW cw) {
  __shared__ __align__(16) char sm[16640];
  conv_dispatch(blockIdx.x, cw, sm);
}

// ================================================================ MFMA GEMM
// BM=128, BN in {64,128}; BK=64; 4 waves, wave tile 64 x BN/2.
// A/B bf16 via global_load_lds, counted-vmcnt double buffer. Flattened 1D
// grid; blocks past nx*ny*gz run carrier conv tiles.
// MODE: 0=qkv scatter  1=split-K f32 partial  2=SwiGLU dual  3=head
template <int BN, int MODE, int SC>
__global__ __launch_bounds__(256) void mm(
    const __bf16* __restrict__ A,
    const __bf16* __restrict__ B0w, const __bf16* __restrict__ B1w,
    const float* __restrict__ bias0, const float* __restrict__ bias1,
    const float* __restrict__ part,
    float* __restrict__ po, __bf16* __restrict__ ob,
    __bf16* __restrict__ qout, __bf16* __restrict__ kout, __bf16* __restrict__ vout,
    int N, int lda, int ldb, int Ktot,
    int nx, int ny, int gz, ConvW cw, int convoff) {
  constexpr int DUAL = (MODE == 2) ? 2 : 1;
  constexpr int FN = BN / 32;
  constexpr int BL = (BN == 128) ? 4 : 2 * DUAL;
  constexpr int ASZ = 32768;                 // [2][8][128][8] bf16
  constexpr int BSZ = DUAL * BN * 256;       // [2][DUAL][8][BN][8] bf16
  __shared__ __align__(16) char smem[ASZ + BSZ];
  const int bid = blockIdx.x;
  const int ncomp = nx * ny * gz;
  if (bid >= ncomp) {
    conv_dispatch(convoff + (bid - ncomp), cw, smem);
    return;
  }
  typedef __bf16 (*AsP)[8][128][8];
  typedef __bf16 (*BsP)[DUAL][8][BN][8];
  AsP As = (AsP)smem;
  BsP Bs = (BsP)(smem + ASZ);
  const int bz = bid / (nx * ny);
  const int r2 = bid - bz * nx * ny;
  const int by = r2 / nx, bx = r2 - by * nx;
  const int tid = threadIdx.x, lane = tid & 63, wave = tid >> 6;
  const int m0 = by << 7, n0 = bx * BN;
  const int wm0 = (wave >> 1) * 64, wn0 = (wave & 1) * (BN / 2);
  const int lr = lane & 15, kh = lane >> 4;

  const int ktiles = Ktot >> 6;
  const int nt0 = (ktiles + gz - 1) / gz;
  const int tbeg = bz * nt0;
  const int tend = (ktiles < tbeg + nt0) ? ktiles : (tbeg + nt0);
  const int nt = tend - tbeg;

  f32x4 acc[DUAL][4][FN];
#pragma unroll
  for (int d = 0; d < DUAL; ++d)
#pragma unroll
    for (int mi = 0; mi < 4; ++mi)
#pragma unroll
      for (int fn = 0; fn < FN; ++fn) acc[d][mi][fn] = (f32x4){0.f, 0.f, 0.f, 0.f};

  auto STAGE = [&](int buf, int t) {
    const int k0 = (tbeg + t) << 6;
#pragma unroll
    for (int i = 0; i < 4; ++i) {
      const int d = i * 256 + tid;
      gl_lds16(A + (size_t)(m0 + (d & 127)) * lda + k0 + (d >> 7) * 8,
               &As[buf][d >> 7][d & 127][0]);
    }
    if (BN == 128) {
#pragma unroll
      for (int i = 0; i < 4; ++i) {
        const int d = i * 256 + tid;
        gl_lds16(B0w + (size_t)(n0 + (d & 127)) * ldb + k0 + (d >> 7) * 8,
                 &Bs[buf][0][d >> 7][d & 127][0]);
      }
    } else {
#pragma unroll
      for (int i = 0; i < 2; ++i) {
        const int d = i * 256 + tid;
        gl_lds16(B0w + (size_t)(n0 + (d & 63)) * ldb + k0 + (d >> 6) * 8,
                 &Bs[buf][0][d >> 6][d & 63][0]);
      }
      if (DUAL == 2) {
#pragma unroll
        for (int i = 0; i < 2; ++i) {
          const int d = i * 256 + tid;
          gl_lds16(B1w + (size_t)(n0 + (d & 63)) * ldb + k0 + (d >> 6) * 8,
                   &Bs[buf][DUAL - 1][d >> 6][d & 63][0]);
        }
      }
    }
  };
  auto COMP = [&](int buf) {
#pragma unroll
    for (int ks = 0; ks < 2; ++ks) {
      const int kidx = ks * 4 + kh;
      bf16x8 af[4];
#pragma unroll
      for (int mi = 0; mi < 4; ++mi)
        af[mi] = *(const bf16x8*)&As[buf][kidx][wm0 + mi * 16 + lr][0];
#pragma unroll
      for (int d = 0; d < DUAL; ++d)
#pragma unroll
        for (int fn = 0; fn < FN; ++fn) {
          bf16x8 bfr = *(const bf16x8*)&Bs[buf][d][kidx][wn0 + fn * 16 + lr][0];
#pragma unroll
          for (int mi = 0; mi < 4; ++mi)
            acc[d][mi][fn] = MFMA(af[mi], bfr, acc[d][mi][fn]);
        }
    }
  };

  STAGE(0, 0);
  int cur = 0;
  for (int t = 0; t < nt - 1; ++t) {
    STAGE(cur ^ 1, t + 1);          // next tile stays in flight
    vmwait<4 + BL>();               // own tile-t loads retired
    __builtin_amdgcn_s_barrier();
    COMP(cur);
    __builtin_amdgcn_s_barrier();
    cur ^= 1;
  }
  vmwait<0>();
  __builtin_amdgcn_s_barrier();
  COMP(cur);

  float sc = 1.0f;
  if (SC) {
    __shared__ float smr[4];
    float s = part[tid];
#pragma unroll
    for (int o = 32; o > 0; o >>= 1) s += __shfl_down(s, o);
    if ((tid & 63) == 0) smr[tid >> 6] = s;
    __syncthreads();
    sc = 1.0f / sqrtf((smr[0] + smr[1] + smr[2] + smr[3]) / (float)NELEM + EPSF);
  }

#pragma unroll
  for (int mi = 0; mi < 4; ++mi)
#pragma unroll
    for (int fn = 0; fn < FN; ++fn) {
      const int col = n0 + wn0 + fn * 16 + lr;
      if (MODE == 0) {
        const float bs = bias0[col];
        const int h = col / (3 * HDIM);
        const int rsel = (col >> 6) % 3;
        const int s2 = col & (HDIM - 1);
#pragma unroll
        for (int j = 0; j < 4; ++j) {
          const int row = m0 + wm0 + mi * 16 + (kh << 2) + j;
          const int b = row >> 9, t = row & (TSEQ - 1);
          const float v = acc[0][mi][fn][j] * sc + bs;
          if (rsel == 0)      qout[((size_t)(b * NHEAD + h) * TSEQ + t) * HDIM + s2] = (__bf16)v;
          else if (rsel == 1) kout[((size_t)(b * NHEAD + h) * TSEQ + t) * HDIM + s2] = (__bf16)v;
          else                vout[((size_t)(b * NHEAD + h) * HDIM + s2) * TSEQ + t] = (__bf16)v;
        }
      } else if (MODE == 1) {
        float* pz = po + (size_t)bz * NELEM;
#pragma unroll
        for (int j = 0; j < 4; ++j) {
          const int row = m0 + wm0 + mi * 16 + (kh << 2) + j;
          pz[(size_t)row * EDIM + col] = acc[0][mi][fn][j];
        }
      } else if (MODE == 2) {
        const bool ok = col < N;
        const float bb1 = ok ? bias0[col] : 0.f;
        const float bb3 = ok ? bias1[col] : 0.f;
#pragma unroll
        for (int j = 0; j < 4; ++j) {
          const int row = m0 + wm0 + mi * 16 + (kh << 2) + j;
          float v = 0.f;
          if (ok) {
            const float a1v = acc[0][mi][fn][j] * sc + bb1;
            const float a3v = acc[DUAL - 1][mi][fn][j] * sc + bb3;
            v = a1v * (1.0f / (1.0f + __expf(-a1v))) * a3v;
          }
          ob[(size_t)row * DPAD + col] = (__bf16)v;
        }
      } else {
        if (col < N) {
          const float bs = bias0[col];
#pragma unroll
          for (int j = 0; j < 4; ++j) {
            const int row = m0 + wm0 + mi * 16 + (kh << 2) + j;
            po[(size_t)row * N + col] = acc[0][mi][fn][j] * sc + bs;
          }
        }
      }
    }
}

// ------------------------------------------------- flash attention (bf16 in)
// 32-row Q tiles; 512 compute blocks + carrier conv blocks. dbuf K/V,
// counted vmcnt, defer-max THR=8.
__global__ __launch_bounds__(256) void k_flash(const __bf16* __restrict__ qbuf,
                                               const __bf16* __restrict__ kbuf,
                                               const __bf16* __restrict__ vbufT,
                                               __bf16* __restrict__ y2,
                                               ConvW cw, int convoff) {
  __shared__ __align__(16) char smem[41472];
  const int bid = blockIdx.x;
  if (bid >= 512) {
    conv_dispatch(convoff + (bid - 512), cw, smem);
    return;
  }
  const int qt = bid & 15, bh = bid >> 4;
  const int b = bh >> 4, h = bh & 15;
  const int m0 = qt << 5;
  const __bf16* qp = qbuf  + (size_t)bh * TSEQ * HDIM;
  const __bf16* kp = kbuf  + (size_t)bh * TSEQ * HDIM;
  const __bf16* vp = vbufT + (size_t)bh * HDIM * TSEQ;   // [d][t]
  __bf16 (*Qs)[32][8]    = (__bf16 (*)[32][8])smem;                    // 4KB
  __bf16 (*Ks)[8][64][8] = (__bf16 (*)[8][64][8])(smem + 4096);        // 16KB
  __bf16 (*Vs)[8][64][8] = (__bf16 (*)[8][64][8])(smem + 20480);       // 16KB
  __bf16 (*Ps)[32][8]    = (__bf16 (*)[32][8])(smem + 36864);          // 4KB
  float* wmaxp = (float*)(smem + 40960);                               // [2][32]
  float* wsump = wmaxp + 64;                                           // [2][32]
  const int tid = threadIdx.x, lane = tid & 63, wave = tid >> 6;
  const int wm = (wave >> 1) << 4, wn = (wave & 1) << 5;
  const int lr = lane & 15, kh = lane >> 4;

  auto STAGE_KV = [&](int kt2, int buf) {
    const int n0s = kt2 << 6;
#pragma unroll
    for (int i = 0; i < 2; ++i) {
      const int d = i * 256 + tid;
      const int kb2 = d >> 6, row = d & 63;
      gl_lds16(kp + (size_t)(n0s + row) * HDIM + kb2 * 8, &Ks[buf][kb2][row][0]);
      gl_lds16(vp + (size_t)row * TSEQ + n0s + kb2 * 8, &Vs[buf][kb2][row][0]);
    }
  };

  gl_lds16(qp + (size_t)(m0 + (tid & 31)) * HDIM + (tid >> 5) * 8,
           &Qs[tid >> 5][tid & 31][0]);
  STAGE_KV(0, 0);

  float m_[4], l_[4];
#pragma unroll
  for (int j = 0; j < 4; ++j) { m_[j] = NEGBIG; l_[j] = 0.f; }
  f32x4 o0 = {0, 0, 0, 0}, o1 = {0, 0, 0, 0};

  const int ktmax = qt >> 1;
  int cur = 0;
  for (int kt = 0; kt <= ktmax; ++kt) {
    const int n0 = kt << 6;
    if (kt < ktmax) {
      STAGE_KV(kt + 1, cur ^ 1);
      vmwait<4>();
    } else {
      vmwait<0>();
    }
    __builtin_amdgcn_s_barrier();

    f32x4 s0 = {0, 0, 0, 0}, s1 = {0, 0, 0, 0};
#pragma unroll
    for (int ks = 0; ks < 2; ++ks) {
      const int kidx = ks * 4 + kh;
      bf16x8 a  = *(const bf16x8*)&Qs[kidx][wm + lr][0];
      bf16x8 b0 = *(const bf16x8*)&Ks[cur][kidx][wn + lr][0];
      bf16x8 b1 = *(const bf16x8*)&Ks[cur][kidx][wn + 16 + lr][0];
      s0 = MFMA(a, b0, s0); s1 = MFMA(a, b1, s1);
    }
    float pv0[4], pv1[4];
#pragma unroll
    for (int j = 0; j < 4; ++j) {
      const int grow = m0 + wm + (kh << 2) + j;
      float t0 = s0[j] * SCALEF; if (n0 + wn + lr > grow)      t0 = NEGBIG;
      float t1 = s1[j] * SCALEF; if (n0 + wn + 16 + lr > grow) t1 = NEGBIG;
      pv0[j] = t0; pv1[j] = t1;
      float v = fmaxf(t0, t1);
      v = fmaxf(v, __shfl_xor(v, 1)); v = fmaxf(v, __shfl_xor(v, 2));
      v = fmaxf(v, __shfl_xor(v, 4)); v = fmaxf(v, __shfl_xor(v, 8));
      wmaxp[(wave & 1) * 32 + wm + (kh << 2) + j] = v;
    }
    lgkm_barrier();

    float tmax[4]; bool need = false;
#pragma unroll
    for (int j = 0; j < 4; ++j) {
      const int rl = wm + (kh << 2) + j;
      tmax[j] = fmaxf(wmaxp[rl], wmaxp[32 + rl]);
      need |= (tmax[j] > m_[j] + 8.f);
    }
    if (__ballot(need)) {
#pragma unroll
      for (int j = 0; j < 4; ++j) {
        const float mn = fmaxf(m_[j], tmax[j]);
        const float al = __expf(m_[j] - mn);
        m_[j] = mn; l_[j] *= al; o0[j] *= al; o1[j] *= al;
      }
    }
#pragma unroll
    for (int j = 0; j < 4; ++j) {
      const float p0 = __expf(pv0[j] - m_[j]);
      const float p1 = __expf(pv1[j] - m_[j]);
      float rs = p0 + p1;
      rs += __shfl_xor(rs, 1); rs += __shfl_xor(rs, 2);
      rs += __shfl_xor(rs, 4); rs += __shfl_xor(rs, 8);
      const int rl = wm + (kh << 2) + j;
      wsump[(wave & 1) * 32 + rl] = rs;
      const int pc0 = wn + lr, pc1 = wn + 16 + lr;
      Ps[pc0 >> 3][rl][pc0 & 7] = (__bf16)p0;
      Ps[pc1 >> 3][rl][pc1 & 7] = (__bf16)p1;
    }
    lgkm_barrier();

#pragma unroll
    for (int j = 0; j < 4; ++j) {
      const int rl = wm + (kh << 2) + j;
      l_[j] += wsump[rl] + wsump[32 + rl];
    }
#pragma unroll
    for (int ks = 0; ks < 2; ++ks) {
      const int kidx = ks * 4 + kh;
      bf16x8 a  = *(const bf16x8*)&Ps[kidx][wm + lr][0];
      bf16x8 b0 = *(const bf16x8*)&Vs[cur][kidx][wn + lr][0];
      bf16x8 b1 = *(const bf16x8*)&Vs[cur][kidx][wn + 16 + lr][0];
      o0 = MFMA(a, b0, o0); o1 = MFMA(a, b1, o1);
    }
    __builtin_amdgcn_s_barrier();
    cur ^= 1;
  }

#pragma unroll
  for (int j = 0; j < 4; ++j) {
    const int row = m0 + wm + (kh << 2) + j;
    const float inv = 1.0f / l_[j];
    y2[((size_t)(b * TSEQ) + row) * EDIM + h * HDIM + wn + lr]      = (__bf16)(o0[j] * inv);
    y2[((size_t)(b * TSEQ) + row) * EDIM + h * HDIM + wn + 16 + lr] = (__bf16)(o1[j] * inv);
  }
}

// ---------------------------------------------------------------- launcher
extern "C" void kernel_launch(void* const* d_in, const int* in_sizes, int n_in,
                              void* d_out, int out_size, void* d_ws, size_t ws_size,
                              hipStream_t stream) {
  const int*   tokens  = (const int*)d_in[0];
  const float* emb     = (const float*)d_in[1];
  const float* Wqkv    = (const float*)d_in[2];
  const float* bqkv    = (const float*)d_in[3];
  const float* Wo      = (const float*)d_in[4];
  const float* bo      = (const float*)d_in[5];
  const float* W1      = (const float*)d_in[6];
  const float* b1      = (const float*)d_in[7];
  const float* W3      = (const float*)d_in[8];
  const float* b3      = (const float*)d_in[9];
  const float* W2w     = (const float*)d_in[10];
  const float* b2      = (const float*)d_in[11];
  const float* g_mha   = (const float*)d_in[12];
  const float* g_ff    = (const float*)d_in[13];
  const float* g_final = (const float*)d_in[14];
  const float* Wout    = (const float*)d_in[15];
  const float* bout    = (const float*)d_in[16];
  float* out = (float*)d_out;

  char* base = (char*)d_ws;
  size_t off = 0;
  auto alloc = [&](size_t bytes) { char* p = base + off; off = (off + bytes + 255) & ~(size_t)255; return p; };
  float*  x    = (float*)alloc(4u << 20);
  float*  part = (float*)alloc(2048);
  __bf16* ybf  = (__bf16*)alloc(2u << 20);
  __bf16* qbf  = (__bf16*)alloc(2u << 20);
  __bf16* kbf  = (__bf16*)alloc(2u << 20);
  __bf16* vbT  = (__bf16*)alloc(2u << 20);
  __bf16* y2bf = (__bf16*)alloc(2u << 20);
  __bf16* ubf  = (__bf16*)alloc((size_t)MTOK * DPAD * 2);
  float*  pbuf = (float*)alloc((size_t)4 * NELEM * 4);
  __bf16* WoutT = (__bf16*)alloc((size_t)8192 * 1024 * 2);
  __bf16* qkvT = (__bf16*)alloc((size_t)NLAYER * 3072 * 1024 * 2);
  __bf16* woT  = (__bf16*)alloc((size_t)NLAYER * 1024 * 1024 * 2);
  __bf16* w1T  = (__bf16*)alloc((size_t)NLAYER * DPAD * 1024 * 2);
  __bf16* w3T  = (__bf16*)alloc((size_t)NLAYER * DPAD * 1024 * 2);
  __bf16* w2T  = (__bf16*)alloc((size_t)NLAYER * 1024 * DPAD * 2);

  ConvW cw;
  cw.Wqkv = Wqkv; cw.Wo = Wo; cw.W1 = W1; cw.W3 = W3; cw.W2w = W2w;
  cw.g_mha = g_mha; cw.g_ff = g_ff; cw.Wout = Wout; cw.g_final = g_final;
  cw.qkvT = qkvT; cw.woT = woT; cw.w1T = w1T; cw.w3T = w3T; cw.w2T = w2T;
  cw.WoutT = WoutT;

  k_embed<<<MTOK, 256, 0, stream>>>(tokens, emb, x);
  k_conv0<<<LCONV, 256, 0, stream>>>(cw);              // layer-0 weights only
  k_red1f<<<256, 256, 0, stream>>>(x, nullptr, 0, nullptr, part, ybf);

  const float* pend_bias = nullptr;
  for (int l = 0; l < NLAYER; ++l) {
    // carriers convert layer l+1 (or the head when l==23)
    const int co = (l + 1 < NLAYER) ? (l + 1) * LCONV : ACONV;
    const int cn = (l + 1 < NLAYER) ? 772 : 512;       // 4 carrier groups/layer
    // --- MHA ---
    mm<64, 0, 1><<<384 + cn, 256, 0, stream>>>(
        ybf, qkvT + (size_t)l * 3072 * 1024, nullptr,
        bqkv + (size_t)l * 3 * EDIM, nullptr, part,
        nullptr, nullptr, qbf, kbf, vbT, 3072, 1024, 1024, 1024,
        48, 8, 1, cw, co);
    k_flash<<<512 + cn, 256, 0, stream>>>(qbf, kbf, vbT, y2bf, cw, co + cn);
    mm<64, 1, 0><<<512, 256, 0, stream>>>(
        y2bf, woT + (size_t)l * 1024 * 1024, nullptr,
        nullptr, nullptr, nullptr,
        pbuf, nullptr, nullptr, nullptr, nullptr, 1024, 1024, 1024, 1024,
        16, 8, 4, cw, 0);
    // --- SwiGLU FFN ---
    k_red1f<<<256, 256, 0, stream>>>(x, pbuf, 4, bo + (size_t)l * EDIM, part, ybf);
    mm<64, 2, 1><<<344 + cn, 256, 0, stream>>>(
        ybf, w1T + (size_t)l * DPAD * 1024, w3T + (size_t)l * DPAD * 1024,
        b1 + (size_t)l * DFFDIM, b3 + (size_t)l * DFFDIM, part,
        nullptr, ubf, nullptr, nullptr, nullptr, DFFDIM, 1024, 1024, 1024,
        43, 8, 1, cw, co + 2 * cn);
    mm<64, 1, 0><<<512 + cn, 256, 0, stream>>>(
        ubf, w2T + (size_t)l * 1024 * DPAD, nullptr,
        nullptr, nullptr, nullptr,
        pbuf, nullptr, nullptr, nullptr, nullptr, 1024, DPAD, DPAD, DPAD,
        16, 8, 4, cw, co + 3 * cn);
    pend_bias = b2 + (size_t)l * EDIM;
    // fold w2 partials + b2; emits next layer's (or head's) ybf/part
    k_red1f<<<256, 256, 0, stream>>>(x, pbuf, 4, pend_bias, part, ybf);
  }

  // --- vocab head ---
  mm<128, 3, 1><<<512, 256, 0, stream>>>(
      ybf, WoutT, nullptr, bout, nullptr, part,
      out, nullptr, nullptr, nullptr, nullptr, VOCAB, 1024, 1024, 1024,
      64, 8, 1, cw, 0);
}

// Round 19
// 3528.091 us; speedup vs baseline: 2.0780x; 1.0307x over previous
//
#include <hip/hip_runtime.h>
#include <hip/hip_bf16.h>
#include <math.h>

#define EDIM   1024
#define TSEQ   512
#define NBATCH 2
#define NHEAD  16
#define HDIM   64
#define NLAYER 24
#define VOCAB  8124
#define DFFDIM 2730
#define DPAD   2752              // 43*64 padded SwiGLU width
#define MTOK   (NBATCH*TSEQ)     // 1024
#define NELEM  (MTOK*EDIM)
#define EPSF   1e-5f
#define SCALEF (1.0f/32.0f)
#define NEGBIG (-1e30f)
#define LCONV  3088              // conv tiles per layer
#define ACONV  (NLAYER*LCONV)    // 74112, then head tiles follow
#define HCONV  2048
#define RGRID  512               // red1f blocks (2/CU)

typedef __bf16 bf16x8 __attribute__((ext_vector_type(8)));
typedef __bf16 bf16x4 __attribute__((ext_vector_type(4)));
typedef float  f32x4  __attribute__((ext_vector_type(4)));

#define MFMA(a, b, c) __builtin_amdgcn_mfma_f32_16x16x32_bf16((a), (b), (c), 0, 0, 0)

__device__ __forceinline__ void gl_lds16(const __bf16* g, __bf16* l) {
  __builtin_amdgcn_global_load_lds(
      (const __attribute__((address_space(1))) void*)g,
      (__attribute__((address_space(3))) void*)l, 16, 0, 0);
}
template <int N> __device__ __forceinline__ void vmwait() {
  asm volatile("s_waitcnt vmcnt(%0)" :: "n"(N) : "memory");
}
__device__ __forceinline__ void lgkm_barrier() {
  asm volatile("s_waitcnt lgkmcnt(0)" ::: "memory");
  __builtin_amdgcn_s_barrier();
}

// ---------------- weight pointers bundle (for carrier conv blocks)
struct ConvW {
  const float *Wqkv, *Wo, *W1, *W3, *W2w, *g_mha, *g_ff, *Wout, *g_final;
  __bf16 *qkvT, *woT, *w1T, *w3T, *w2T, *WoutT;
};

// ---------------------------------------------------------------- embedding+PE
__global__ __launch_bounds__(256) void k_embed(const int* __restrict__ tok,
                                               const float* __restrict__ emb,
                                               float* __restrict__ x) {
  const int bt = blockIdx.x;
  const int t  = bt & (TSEQ - 1);
  const int tk = tok[bt];
  const float* er = emb + (size_t)tk * EDIM;
  float* xr = x + (size_t)bt * EDIM;
  for (int e = threadIdx.x * 4; e < EDIM; e += 256 * 4) {
    float4 v = *(const float4*)(er + e);
    float vv[4] = {v.x, v.y, v.z, v.w};
    float ou[4];
#pragma unroll
    for (int j = 0; j < 4; ++j) {
      int ee = e + j;
      int i2 = ee & ~1;
      float freq = expf(-(float)i2 * (9.210340371976184f / 1024.0f));
      float ang  = (float)t * freq;
      ou[j] = vv[j] + ((ee & 1) ? cosf(ang) : sinf(ang));
    }
    *(float4*)(xr + e) = make_float4(ou[0], ou[1], ou[2], ou[3]);
  }
}

// ----------------- RMS reduce (+fold 4 partials) + emit bf16(x). RGRID blocks.
__global__ __launch_bounds__(256) void k_red1f(float* __restrict__ x,
                                               const float* __restrict__ pb,
                                               int np,
                                               const float* __restrict__ bias,
                                               float* __restrict__ part,
                                               __bf16* __restrict__ ybf) {
  const int tid = threadIdx.x;
  float s = 0.f;
  const bool fold = (pb != nullptr);
  for (int i = (blockIdx.x * 256 + tid) * 4; i < NELEM; i += RGRID * 256 * 4) {
    float4 v = *(const float4*)(x + i);
    if (fold) {
      for (int z = 0; z < np; ++z) {
        float4 a = *(const float4*)(pb + (size_t)z * NELEM + i);
        v.x += a.x; v.y += a.y; v.z += a.z; v.w += a.w;
      }
      float4 c = *(const float4*)(bias + (i & (EDIM - 1)));
      v.x += c.x; v.y += c.y; v.z += c.z; v.w += c.w;
      *(float4*)(x + i) = v;
    }
    bf16x4 o = {(__bf16)v.x, (__bf16)v.y, (__bf16)v.z, (__bf16)v.w};
    *(bf16x4*)(ybf + i) = o;
    s += v.x * v.x + v.y * v.y + v.z * v.z + v.w * v.w;
  }
#pragma unroll
  for (int o = 32; o > 0; o >>= 1) s += __shfl_down(s, o);
  __shared__ float sm[4];
  if ((tid & 63) == 0) sm[tid >> 6] = s;
  __syncthreads();
  if (tid == 0) part[blockIdx.x] = sm[0] + sm[1] + sm[2] + sm[3];
}

// ------------------------------------------------- weight convert + transpose
__device__ void conv_tile(const float* __restrict__ src,
                          const float* __restrict__ gk,
                          __bf16* __restrict__ dst,
                          int K, int N, int Kpad, int tk, int tn, char* smv) {
  float (*st)[65] = (float (*)[65])smv;   // 64 x 65 f32 = 16,640 B
  const int k0 = tk << 6, n0 = tn << 6;
  const int tid = threadIdx.x;
  {
    const int r0 = tid >> 4, c4 = (tid & 15) << 2;
#pragma unroll
    for (int i = 0; i < 4; ++i) {
      const int r = r0 + i * 16;
      const int k = k0 + r;
      f32x4 v = {0.f, 0.f, 0.f, 0.f};
      if (k < K) {
        const float* sp = src + (size_t)k * N + n0 + c4;
        if (n0 + c4 + 3 < N) v = __builtin_nontemporal_load((const f32x4*)sp);
        else {
          if (n0 + c4 + 0 < N) v[0] = sp[0];
          if (n0 + c4 + 1 < N) v[1] = sp[1];
          if (n0 + c4 + 2 < N) v[2] = sp[2];
          if (n0 + c4 + 3 < N) v[3] = sp[3];
        }
        if (gk) {
          const float gv = gk[k];
          v[0] *= gv; v[1] *= gv; v[2] *= gv; v[3] *= gv;
        }
      }
      st[r][c4 + 0] = v[0]; st[r][c4 + 1] = v[1];
      st[r][c4 + 2] = v[2]; st[r][c4 + 3] = v[3];
    }
  }
  __syncthreads();
  {
    const int nl0 = tid >> 3, c8 = (tid & 7) << 3;
#pragma unroll
    for (int i = 0; i < 2; ++i) {
      const int nl = nl0 + i * 32;
      bf16x8 o = {(__bf16)st[c8 + 0][nl], (__bf16)st[c8 + 1][nl],
                  (__bf16)st[c8 + 2][nl], (__bf16)st[c8 + 3][nl],
                  (__bf16)st[c8 + 4][nl], (__bf16)st[c8 + 5][nl],
                  (__bf16)st[c8 + 6][nl], (__bf16)st[c8 + 7][nl]};
      *(bf16x8*)&dst[(size_t)(n0 + nl) * Kpad + k0 + c8] = o;
    }
  }
}

// global conv tile space: [0, ACONV) layer tiles; [ACONV, ACONV+HCONV) head.
__device__ void conv_dispatch(int g, const ConvW& cw, char* sm) {
  if (g < ACONV) {
    const int l = g / LCONV;
    int b = g - l * LCONV;
    if (b < 768) {
      conv_tile(cw.Wqkv + (size_t)l * 1024 * 3072, cw.g_mha + (size_t)l * EDIM,
                cw.qkvT + (size_t)l * 3072 * 1024, 1024, 3072, 1024,
                b / 48, b % 48, sm);
    } else if (b < 1024) {
      int t = b - 768;
      conv_tile(cw.Wo + (size_t)l * 1024 * 1024, nullptr,
                cw.woT + (size_t)l * 1024 * 1024, 1024, 1024, 1024,
                t / 16, t % 16, sm);
    } else if (b < 1712) {
      int t = b - 1024;
      conv_tile(cw.W1 + (size_t)l * 1024 * DFFDIM, cw.g_ff + (size_t)l * EDIM,
                cw.w1T + (size_t)l * DPAD * 1024, 1024, DFFDIM, 1024,
                t / 43, t % 43, sm);
    } else if (b < 2400) {
      int t = b - 1712;
      conv_tile(cw.W3 + (size_t)l * 1024 * DFFDIM, cw.g_ff + (size_t)l * EDIM,
                cw.w3T + (size_t)l * DPAD * 1024, 1024, DFFDIM, 1024,
                t / 43, t % 43, sm);
    } else {
      int t = b - 2400;
      conv_tile(cw.W2w + (size_t)l * DFFDIM * 1024, nullptr,
                cw.w2T + (size_t)l * 1024 * DPAD, DFFDIM, 1024, DPAD,
                t / 16, t % 16, sm);
    }
  } else {
    const int t = g - ACONV;
    conv_tile(cw.Wout, cw.g_final, cw.WoutT, 1024, VOCAB, 1024,
              t >> 7, t & 127, sm);
  }
}

__global__ __launch_bounds__(256) void k_conv0(ConvW cw) {
  __shared__ __align__(16) char sm[16640];
  conv_dispatch(blockIdx.x, cw, sm);
}

// ================================================================ MFMA GEMM
// BM=128, BN in {64,128}; BK=64; 4 waves, wave tile 64 x BN/2.
// A/B bf16 via global_load_lds, counted-vmcnt double buffer. Flattened 1D
// grid; blocks past nx*ny*gz run carrier conv tiles.
// MODE: 0=qkv scatter  1=split-K f32 partial  2=SwiGLU dual  3=head
template <int BN, int MODE, int SC>
__global__ __launch_bounds__(256) void mm(
    const __bf16* __restrict__ A,
    const __bf16* __restrict__ B0w, const __bf16* __restrict__ B1w,
    const float* __restrict__ bias0, const float* __restrict__ bias1,
    const float* __restrict__ part,
    float* __restrict__ po, __bf16* __restrict__ ob,
    __bf16* __restrict__ qout, __bf16* __restrict__ kout, __bf16* __restrict__ vout,
    int N, int lda, int ldb, int Ktot,
    int nx, int ny, int gz, ConvW cw, int convoff) {
  constexpr int DUAL = (MODE == 2) ? 2 : 1;
  constexpr int FN = BN / 32;
  constexpr int BL = (BN == 128) ? 4 : 2 * DUAL;
  constexpr int ASZ = 32768;                 // [2][8][128][8] bf16
  constexpr int BSZ = DUAL * BN * 256;       // [2][DUAL][8][BN][8] bf16
  __shared__ __align__(16) char smem[ASZ + BSZ];
  const int bid = blockIdx.x;
  const int ncomp = nx * ny * gz;
  if (bid >= ncomp) {
    conv_dispatch(convoff + (bid - ncomp), cw, smem);
    return;
  }
  typedef __bf16 (*AsP)[8][128][8];
  typedef __bf16 (*BsP)[DUAL][8][BN][8];
  AsP As = (AsP)smem;
  BsP Bs = (BsP)(smem + ASZ);
  const int bz = bid / (nx * ny);
  const int r2 = bid - bz * nx * ny;
  const int by = r2 / nx, bx = r2 - by * nx;
  const int tid = threadIdx.x, lane = tid & 63, wave = tid >> 6;
  const int m0 = by << 7, n0 = bx * BN;
  const int wm0 = (wave >> 1) * 64, wn0 = (wave & 1) * (BN / 2);
  const int lr = lane & 15, kh = lane >> 4;

  const int ktiles = Ktot >> 6;
  const int nt0 = (ktiles + gz - 1) / gz;
  const int tbeg = bz * nt0;
  const int tend = (ktiles < tbeg + nt0) ? ktiles : (tbeg + nt0);
  const int nt = tend - tbeg;

  f32x4 acc[DUAL][4][FN];
#pragma unroll
  for (int d = 0; d < DUAL; ++d)
#pragma unroll
    for (int mi = 0; mi < 4; ++mi)
#pragma unroll
      for (int fn = 0; fn < FN; ++fn) acc[d][mi][fn] = (f32x4){0.f, 0.f, 0.f, 0.f};

  auto STAGE = [&](int buf, int t) {
    const int k0 = (tbeg + t) << 6;
#pragma unroll
    for (int i = 0; i < 4; ++i) {
      const int d = i * 256 + tid;
      gl_lds16(A + (size_t)(m0 + (d & 127)) * lda + k0 + (d >> 7) * 8,
               &As[buf][d >> 7][d & 127][0]);
    }
    if (BN == 128) {
#pragma unroll
      for (int i = 0; i < 4; ++i) {
        const int d = i * 256 + tid;
        gl_lds16(B0w + (size_t)(n0 + (d & 127)) * ldb + k0 + (d >> 7) * 8,
                 &Bs[buf][0][d >> 7][d & 127][0]);
      }
    } else {
#pragma unroll
      for (int i = 0; i < 2; ++i) {
        const int d = i * 256 + tid;
        gl_lds16(B0w + (size_t)(n0 + (d & 63)) * ldb + k0 + (d >> 6) * 8,
                 &Bs[buf][0][d >> 6][d & 63][0]);
      }
      if (DUAL == 2) {
#pragma unroll
        for (int i = 0; i < 2; ++i) {
          const int d = i * 256 + tid;
          gl_lds16(B1w + (size_t)(n0 + (d & 63)) * ldb + k0 + (d >> 6) * 8,
                   &Bs[buf][DUAL - 1][d >> 6][d & 63][0]);
        }
      }
    }
  };
  auto COMP = [&](int buf) {
#pragma unroll
    for (int ks = 0; ks < 2; ++ks) {
      const int kidx = ks * 4 + kh;
      bf16x8 af[4];
#pragma unroll
      for (int mi = 0; mi < 4; ++mi)
        af[mi] = *(const bf16x8*)&As[buf][kidx][wm0 + mi * 16 + lr][0];
#pragma unroll
      for (int d = 0; d < DUAL; ++d)
#pragma unroll
        for (int fn = 0; fn < FN; ++fn) {
          bf16x8 bfr = *(const bf16x8*)&Bs[buf][d][kidx][wn0 + fn * 16 + lr][0];
#pragma unroll
          for (int mi = 0; mi < 4; ++mi)
            acc[d][mi][fn] = MFMA(af[mi], bfr, acc[d][mi][fn]);
        }
    }
  };

  STAGE(0, 0);
  int cur = 0;
  for (int t = 0; t < nt - 1; ++t) {
    STAGE(cur ^ 1, t + 1);          // next tile stays in flight
    vmwait<4 + BL>();               // own tile-t loads retired
    __builtin_amdgcn_s_barrier();
    COMP(cur);
    __builtin_amdgcn_s_barrier();
    cur ^= 1;
  }
  vmwait<0>();
  __builtin_amdgcn_s_barrier();
  COMP(cur);

  float sc = 1.0f;
  if (SC) {
    __shared__ float smr[4];
    float s = part[tid] + part[tid + 256];
#pragma unroll
    for (int o = 32; o > 0; o >>= 1) s += __shfl_down(s, o);
    if ((tid & 63) == 0) smr[tid >> 6] = s;
    __syncthreads();
    sc = 1.0f / sqrtf((smr[0] + smr[1] + smr[2] + smr[3]) / (float)NELEM + EPSF);
  }

#pragma unroll
  for (int mi = 0; mi < 4; ++mi)
#pragma unroll
    for (int fn = 0; fn < FN; ++fn) {
      const int col = n0 + wn0 + fn * 16 + lr;
      if (MODE == 0) {
        const float bs = bias0[col];
        const int h = col / (3 * HDIM);
        const int rsel = (col >> 6) % 3;
        const int s2 = col & (HDIM - 1);
#pragma unroll
        for (int j = 0; j < 4; ++j) {
          const int row = m0 + wm0 + mi * 16 + (kh << 2) + j;
          const int b = row >> 9, t = row & (TSEQ - 1);
          const float v = acc[0][mi][fn][j] * sc + bs;
          if (rsel == 0)      qout[((size_t)(b * NHEAD + h) * TSEQ + t) * HDIM + s2] = (__bf16)v;
          else if (rsel == 1) kout[((size_t)(b * NHEAD + h) * TSEQ + t) * HDIM + s2] = (__bf16)v;
          else                vout[((size_t)(b * NHEAD + h) * HDIM + s2) * TSEQ + t] = (__bf16)v;
        }
      } else if (MODE == 1) {
        float* pz = po + (size_t)bz * NELEM;
#pragma unroll
        for (int j = 0; j < 4; ++j) {
          const int row = m0 + wm0 + mi * 16 + (kh << 2) + j;
          pz[(size_t)row * EDIM + col] = acc[0][mi][fn][j];
        }
      } else if (MODE == 2) {
        const bool ok = col < N;
        const float bb1 = ok ? bias0[col] : 0.f;
        const float bb3 = ok ? bias1[col] : 0.f;
#pragma unroll
        for (int j = 0; j < 4; ++j) {
          const int row = m0 + wm0 + mi * 16 + (kh << 2) + j;
          float v = 0.f;
          if (ok) {
            const float a1v = acc[0][mi][fn][j] * sc + bb1;
            const float a3v = acc[DUAL - 1][mi][fn][j] * sc + bb3;
            v = a1v * (1.0f / (1.0f + __expf(-a1v))) * a3v;
          }
          ob[(size_t)row * DPAD + col] = (__bf16)v;
        }
      } else {
        if (col < N) {
          const float bs = bias0[col];
#pragma unroll
          for (int j = 0; j < 4; ++j) {
            const int row = m0 + wm0 + mi * 16 + (kh << 2) + j;
            po[(size_t)row * N + col] = acc[0][mi][fn][j] * sc + bs;
          }
        }
      }
    }
}

// ------------------------------------------------- flash attention (bf16 in)
// 32-row Q tiles; 512 compute blocks + carrier conv blocks. dbuf K/V,
// counted vmcnt, defer-max THR=8.
__global__ __launch_bounds__(256) void k_flash(const __bf16* __restrict__ qbuf,
                                               const __bf16* __restrict__ kbuf,
                                               const __bf16* __restrict__ vbufT,
                                               __bf16* __restrict__ y2,
                                               ConvW cw, int convoff) {
  __shared__ __align__(16) char smem[41472];
  const int bid = blockIdx.x;
  if (bid >= 512) {
    conv_dispatch(convoff + (bid - 512), cw, smem);
    return;
  }
  const int qt = bid & 15, bh = bid >> 4;
  const int b = bh >> 4, h = bh & 15;
  const int m0 = qt << 5;
  const __bf16* qp = qbuf  + (size_t)bh * TSEQ * HDIM;
  const __bf16* kp = kbuf  + (size_t)bh * TSEQ * HDIM;
  const __bf16* vp = vbufT + (size_t)bh * HDIM * TSEQ;   // [d][t]
  __bf16 (*Qs)[32][8]    = (__bf16 (*)[32][8])smem;                    // 4KB
  __bf16 (*Ks)[8][64][8] = (__bf16 (*)[8][64][8])(smem + 4096);        // 16KB
  __bf16 (*Vs)[8][64][8] = (__bf16 (*)[8][64][8])(smem + 20480);       // 16KB
  __bf16 (*Ps)[32][8]    = (__bf16 (*)[32][8])(smem + 36864);          // 4KB
  float* wmaxp = (float*)(smem + 40960);                               // [2][32]
  float* wsump = wmaxp + 64;                                           // [2][32]
  const int tid = threadIdx.x, lane = tid & 63, wave = tid >> 6;
  const int wm = (wave >> 1) << 4, wn = (wave & 1) << 5;
  const int lr = lane & 15, kh = lane >> 4;

  auto STAGE_KV = [&](int kt2, int buf) {
    const int n0s = kt2 << 6;
#pragma unroll
    for (int i = 0; i < 2; ++i) {
      const int d = i * 256 + tid;
      const int kb2 = d >> 6, row = d & 63;
      gl_lds16(kp + (size_t)(n0s + row) * HDIM + kb2 * 8, &Ks[buf][kb2][row][0]);
      gl_lds16(vp + (size_t)row * TSEQ + n0s + kb2 * 8, &Vs[buf][kb2][row][0]);
    }
  };

  gl_lds16(qp + (size_t)(m0 + (tid & 31)) * HDIM + (tid >> 5) * 8,
           &Qs[tid >> 5][tid & 31][0]);
  STAGE_KV(0, 0);

  float m_[4], l_[4];
#pragma unroll
  for (int j = 0; j < 4; ++j) { m_[j] = NEGBIG; l_[j] = 0.f; }
  f32x4 o0 = {0, 0, 0, 0}, o1 = {0, 0, 0, 0};

  const int ktmax = qt >> 1;
  int cur = 0;
  for (int kt = 0; kt <= ktmax; ++kt) {
    const int n0 = kt << 6;
    if (kt < ktmax) {
      STAGE_KV(kt + 1, cur ^ 1);
      vmwait<4>();
    } else {
      vmwait<0>();
    }
    __builtin_amdgcn_s_barrier();

    f32x4 s0 = {0, 0, 0, 0}, s1 = {0, 0, 0, 0};
#pragma unroll
    for (int ks = 0; ks < 2; ++ks) {
      const int kidx = ks * 4 + kh;
      bf16x8 a  = *(const bf16x8*)&Qs[kidx][wm + lr][0];
      bf16x8 b0 = *(const bf16x8*)&Ks[cur][kidx][wn + lr][0];
      bf16x8 b1 = *(const bf16x8*)&Ks[cur][kidx][wn + 16 + lr][0];
      s0 = MFMA(a, b0, s0); s1 = MFMA(a, b1, s1);
    }
    float pv0[4], pv1[4];
#pragma unroll
    for (int j = 0; j < 4; ++j) {
      const int grow = m0 + wm + (kh << 2) + j;
      float t0 = s0[j] * SCALEF; if (n0 + wn + lr > grow)      t0 = NEGBIG;
      float t1 = s1[j] * SCALEF; if (n0 + wn + 16 + lr > grow) t1 = NEGBIG;
      pv0[j] = t0; pv1[j] = t1;
      float v = fmaxf(t0, t1);
      v = fmaxf(v, __shfl_xor(v, 1)); v = fmaxf(v, __shfl_xor(v, 2));
      v = fmaxf(v, __shfl_xor(v, 4)); v = fmaxf(v, __shfl_xor(v, 8));
      wmaxp[(wave & 1) * 32 + wm + (kh << 2) + j] = v;
    }
    lgkm_barrier();

    float tmax[4]; bool need = false;
#pragma unroll
    for (int j = 0; j < 4; ++j) {
      const int rl = wm + (kh << 2) + j;
      tmax[j] = fmaxf(wmaxp[rl], wmaxp[32 + rl]);
      need |= (tmax[j] > m_[j] + 8.f);
    }
    if (__ballot(need)) {
#pragma unroll
      for (int j = 0; j < 4; ++j) {
        const float mn = fmaxf(m_[j], tmax[j]);
        const float al = __expf(m_[j] - mn);
        m_[j] = mn; l_[j] *= al; o0[j] *= al; o1[j] *= al;
      }
    }
#pragma unroll
    for (int j = 0; j < 4; ++j) {
      const float p0 = __expf(pv0[j] - m_[j]);
      const float p1 = __expf(pv1[j] - m_[j]);
      float rs = p0 + p1;
      rs += __shfl_xor(rs, 1); rs += __shfl_xor(rs, 2);
      rs += __shfl_xor(rs, 4); rs += __shfl_xor(rs, 8);
      const int rl = wm + (kh << 2) + j;
      wsump[(wave & 1) * 32 + rl] = rs;
      const int pc0 = wn + lr, pc1 = wn + 16 + lr;
      Ps[pc0 >> 3][rl][pc0 & 7] = (__bf16)p0;
      Ps[pc1 >> 3][rl][pc1 & 7] = (__bf16)p1;
    }
    lgkm_barrier();

#pragma unroll
    for (int j = 0; j < 4; ++j) {
      const int rl = wm + (kh << 2) + j;
      l_[j] += wsump[rl] + wsump[32 + rl];
    }
#pragma unroll
    for (int ks = 0; ks < 2; ++ks) {
      const int kidx = ks * 4 + kh;
      bf16x8 a  = *(const bf16x8*)&Ps[kidx][wm + lr][0];
      bf16x8 b0 = *(const bf16x8*)&Vs[cur][kidx][wn + lr][0];
      bf16x8 b1 = *(const bf16x8*)&Vs[cur][kidx][wn + 16 + lr][0];
      o0 = MFMA(a, b0, o0); o1 = MFMA(a, b1, o1);
    }
    __builtin_amdgcn_s_barrier();
    cur ^= 1;
  }

#pragma unroll
  for (int j = 0; j < 4; ++j) {
    const int row = m0 + wm + (kh << 2) + j;
    const float inv = 1.0f / l_[j];
    y2[((size_t)(b * TSEQ) + row) * EDIM + h * HDIM + wn + lr]      = (__bf16)(o0[j] * inv);
    y2[((size_t)(b * TSEQ) + row) * EDIM + h * HDIM + wn + 16 + lr] = (__bf16)(o1[j] * inv);
  }
}

// ---------------------------------------------------------------- launcher
extern "C" void kernel_launch(void* const* d_in, const int* in_sizes, int n_in,
                              void* d_out, int out_size, void* d_ws, size_t ws_size,
                              hipStream_t stream) {
  const int*   tokens  = (const int*)d_in[0];
  const float* emb     = (const float*)d_in[1];
  const float* Wqkv    = (const float*)d_in[2];
  const float* bqkv    = (const float*)d_in[3];
  const float* Wo      = (const float*)d_in[4];
  const float* bo      = (const float*)d_in[5];
  const float* W1      = (const float*)d_in[6];
  const float* b1      = (const float*)d_in[7];
  const float* W3      = (const float*)d_in[8];
  const float* b3      = (const float*)d_in[9];
  const float* W2w     = (const float*)d_in[10];
  const float* b2      = (const float*)d_in[11];
  const float* g_mha   = (const float*)d_in[12];
  const float* g_ff    = (const float*)d_in[13];
  const float* g_final = (const float*)d_in[14];
  const float* Wout    = (const float*)d_in[15];
  const float* bout    = (const float*)d_in[16];
  float* out = (float*)d_out;

  char* base = (char*)d_ws;
  size_t off = 0;
  auto alloc = [&](size_t bytes) { char* p = base + off; off = (off + bytes + 255) & ~(size_t)255; return p; };
  float*  x    = (float*)alloc(4u << 20);
  float*  part = (float*)alloc(4096);
  __bf16* ybf  = (__bf16*)alloc(2u << 20);
  __bf16* qbf  = (__bf16*)alloc(2u << 20);
  __bf16* kbf  = (__bf16*)alloc(2u << 20);
  __bf16* vbT  = (__bf16*)alloc(2u << 20);
  __bf16* y2bf = (__bf16*)alloc(2u << 20);
  __bf16* ubf  = (__bf16*)alloc((size_t)MTOK * DPAD * 2);
  float*  pbuf = (float*)alloc((size_t)4 * NELEM * 4);
  __bf16* WoutT = (__bf16*)alloc((size_t)8192 * 1024 * 2);
  __bf16* qkvT = (__bf16*)alloc((size_t)NLAYER * 3072 * 1024 * 2);
  __bf16* woT  = (__bf16*)alloc((size_t)NLAYER * 1024 * 1024 * 2);
  __bf16* w1T  = (__bf16*)alloc((size_t)NLAYER * DPAD * 1024 * 2);
  __bf16* w3T  = (__bf16*)alloc((size_t)NLAYER * DPAD * 1024 * 2);
  __bf16* w2T  = (__bf16*)alloc((size_t)NLAYER * 1024 * DPAD * 2);

  ConvW cw;
  cw.Wqkv = Wqkv; cw.Wo = Wo; cw.W1 = W1; cw.W3 = W3; cw.W2w = W2w;
  cw.g_mha = g_mha; cw.g_ff = g_ff; cw.Wout = Wout; cw.g_final = g_final;
  cw.qkvT = qkvT; cw.woT = woT; cw.w1T = w1T; cw.w3T = w3T; cw.w2T = w2T;
  cw.WoutT = WoutT;

  k_embed<<<MTOK, 256, 0, stream>>>(tokens, emb, x);
  k_conv0<<<LCONV, 256, 0, stream>>>(cw);              // layer-0 weights only
  k_red1f<<<RGRID, 256, 0, stream>>>(x, nullptr, 0, nullptr, part, ybf);

  const float* pend_bias = nullptr;
  for (int l = 0; l < NLAYER; ++l) {
    // carriers convert layer l+1 (or the head when l==23)
    const int co = (l + 1 < NLAYER) ? (l + 1) * LCONV : ACONV;
    const int cn = (l + 1 < NLAYER) ? 772 : 512;       // 4 carrier groups/layer
    // --- MHA ---
    mm<64, 0, 1><<<384 + cn, 256, 0, stream>>>(
        ybf, qkvT + (size_t)l * 3072 * 1024, nullptr,
        bqkv + (size_t)l * 3 * EDIM, nullptr, part,
        nullptr, nullptr, qbf, kbf, vbT, 3072, 1024, 1024, 1024,
        48, 8, 1, cw, co);
    k_flash<<<512 + cn, 256, 0, stream>>>(qbf, kbf, vbT, y2bf, cw, co + cn);
    mm<64, 1, 0><<<512, 256, 0, stream>>>(
        y2bf, woT + (size_t)l * 1024 * 1024, nullptr,
        nullptr, nullptr, nullptr,
        pbuf, nullptr, nullptr, nullptr, nullptr, 1024, 1024, 1024, 1024,
        16, 8, 4, cw, 0);
    // --- SwiGLU FFN ---
    k_red1f<<<RGRID, 256, 0, stream>>>(x, pbuf, 4, bo + (size_t)l * EDIM, part, ybf);
    mm<64, 2, 1><<<344 + cn, 256, 0, stream>>>(
        ybf, w1T + (size_t)l * DPAD * 1024, w3T + (size_t)l * DPAD * 1024,
        b1 + (size_t)l * DFFDIM, b3 + (size_t)l * DFFDIM, part,
        nullptr, ubf, nullptr, nullptr, nullptr, DFFDIM, 1024, 1024, 1024,
        43, 8, 1, cw, co + 2 * cn);
    mm<64, 1, 0><<<512 + cn, 256, 0, stream>>>(
        ubf, w2T + (size_t)l * 1024 * DPAD, nullptr,
        nullptr, nullptr, nullptr,
        pbuf, nullptr, nullptr, nullptr, nullptr, 1024, DPAD, DPAD, DPAD,
        16, 8, 4, cw, co + 3 * cn);
    pend_bias = b2 + (size_t)l * EDIM;
    // fold w2 partials + b2; emits next layer's (or head's) ybf/part
    k_red1f<<<RGRID, 256, 0, stream>>>(x, pbuf, 4, pend_bias, part, ybf);
  }

  // --- vocab head ---
  mm<128, 3, 1><<<512, 256, 0, stream>>>(
      ybf, WoutT, nullptr, bout, nullptr, part,
      out, nullptr, nullptr, nullptr, nullptr, VOCAB, 1024, 1024, 1024,
      64, 8, 1, cw, 0);
}

// Round 21
// 3490.852 us; speedup vs baseline: 2.1002x; 1.0107x over previous
//
#include <hip/hip_runtime.h>
#include <hip/hip_bf16.h>
#include <math.h>

#define EDIM   1024
#define TSEQ   512
#define NBATCH 2
#define NHEAD  16
#define HDIM   64
#define NLAYER 24
#define VOCAB  8124
#define DFFDIM 2730
#define DPAD   2752              // 43*64 padded SwiGLU width
#define MTOK   (NBATCH*TSEQ)     // 1024
#define NELEM  (MTOK*EDIM)
#define EPSF   1e-5f
#define SCALEF (1.0f/32.0f)
#define NEGBIG (-1e30f)
#define LCONV  3088              // conv tiles per layer
#define ACONV  (NLAYER*LCONV)    // 74112, then head tiles follow
#define HCONV  2048
#define RGRID  512               // red1f blocks (2/CU)

typedef __bf16 bf16x8 __attribute__((ext_vector_type(8)));
typedef __bf16 bf16x4 __attribute__((ext_vector_type(4)));
typedef float  f32x4  __attribute__((ext_vector_type(4)));

#define MFMA(a, b, c) __builtin_amdgcn_mfma_f32_16x16x32_bf16((a), (b), (c), 0, 0, 0)

__device__ __forceinline__ void gl_lds16(const __bf16* g, __bf16* l) {
  __builtin_amdgcn_global_load_lds(
      (const __attribute__((address_space(1))) void*)g,
      (__attribute__((address_space(3))) void*)l, 16, 0, 0);
}
template <int N> __device__ __forceinline__ void vmwait() {
  asm volatile("s_waitcnt vmcnt(%0)" :: "n"(N) : "memory");
}
__device__ __forceinline__ void lgkm_barrier() {
  asm volatile("s_waitcnt lgkmcnt(0)" ::: "memory");
  __builtin_amdgcn_s_barrier();
}

// ---------------- weight pointers bundle (for carrier conv blocks)
struct ConvW {
  const float *Wqkv, *Wo, *W1, *W3, *W2w, *g_mha, *g_ff, *Wout, *g_final;
  __bf16 *qkvT, *woT, *w1T, *w3T, *w2T, *WoutT;
};

// ---------------------------------------------------------------- embedding+PE
__global__ __launch_bounds__(256) void k_embed(const int* __restrict__ tok,
                                               const float* __restrict__ emb,
                                               float* __restrict__ x) {
  const int bt = blockIdx.x;
  const int t  = bt & (TSEQ - 1);
  const int tk = tok[bt];
  const float* er = emb + (size_t)tk * EDIM;
  float* xr = x + (size_t)bt * EDIM;
  for (int e = threadIdx.x * 4; e < EDIM; e += 256 * 4) {
    float4 v = *(const float4*)(er + e);
    float vv[4] = {v.x, v.y, v.z, v.w};
    float ou[4];
#pragma unroll
    for (int j = 0; j < 4; ++j) {
      int ee = e + j;
      int i2 = ee & ~1;
      float freq = expf(-(float)i2 * (9.210340371976184f / 1024.0f));
      float ang  = (float)t * freq;
      ou[j] = vv[j] + ((ee & 1) ? cosf(ang) : sinf(ang));
    }
    *(float4*)(xr + e) = make_float4(ou[0], ou[1], ou[2], ou[3]);
  }
}

// ----------------- RMS reduce (+fold NP partials) + emit bf16(x). RGRID blocks.
template <int NP>
__global__ __launch_bounds__(256) void k_red1f(float* __restrict__ x,
                                               const float* __restrict__ pb,
                                               const float* __restrict__ bias,
                                               float* __restrict__ part,
                                               __bf16* __restrict__ ybf) {
  const int tid = threadIdx.x;
  float s = 0.f;
  for (int i = (blockIdx.x * 256 + tid) * 4; i < NELEM; i += RGRID * 256 * 4) {
    float4 v = *(const float4*)(x + i);
    if constexpr (NP > 0) {
      f32x4 a[NP];
#pragma unroll
      for (int z = 0; z < NP; ++z)
        a[z] = __builtin_nontemporal_load((const f32x4*)(pb + (size_t)z * NELEM + i));
      float4 c = *(const float4*)(bias + (i & (EDIM - 1)));
#pragma unroll
      for (int z = 0; z < NP; ++z) {
        v.x += a[z][0]; v.y += a[z][1]; v.z += a[z][2]; v.w += a[z][3];
      }
      v.x += c.x; v.y += c.y; v.z += c.z; v.w += c.w;
      *(float4*)(x + i) = v;
    }
    bf16x4 o = {(__bf16)v.x, (__bf16)v.y, (__bf16)v.z, (__bf16)v.w};
    *(bf16x4*)(ybf + i) = o;
    s += v.x * v.x + v.y * v.y + v.z * v.z + v.w * v.w;
  }
#pragma unroll
  for (int o = 32; o > 0; o >>= 1) s += __shfl_down(s, o);
  __shared__ float sm[4];
  if ((tid & 63) == 0) sm[tid >> 6] = s;
  __syncthreads();
  if (tid == 0) part[blockIdx.x] = sm[0] + sm[1] + sm[2] + sm[3];
}

// ------------------------------------------------- weight convert + transpose
__device__ void conv_tile(const float* __restrict__ src,
                          const float* __restrict__ gk,
                          __bf16* __restrict__ dst,
                          int K, int N, int Kpad, int tk, int tn, char* smv) {
  float (*st)[65] = (float (*)[65])smv;   // 64 x 65 f32 = 16,640 B
  const int k0 = tk << 6, n0 = tn << 6;
  const int tid = threadIdx.x;
  {
    const int r0 = tid >> 4, c4 = (tid & 15) << 2;
#pragma unroll
    for (int i = 0; i < 4; ++i) {
      const int r = r0 + i * 16;
      const int k = k0 + r;
      f32x4 v = {0.f, 0.f, 0.f, 0.f};
      if (k < K) {
        const float* sp = src + (size_t)k * N + n0 + c4;
        if (n0 + c4 + 3 < N) v = __builtin_nontemporal_load((const f32x4*)sp);
        else {
          if (n0 + c4 + 0 < N) v[0] = sp[0];
          if (n0 + c4 + 1 < N) v[1] = sp[1];
          if (n0 + c4 + 2 < N) v[2] = sp[2];
          if (n0 + c4 + 3 < N) v[3] = sp[3];
        }
        if (gk) {
          const float gv = gk[k];
          v[0] *= gv; v[1] *= gv; v[2] *= gv; v[3] *= gv;
        }
      }
      st[r][c4 + 0] = v[0]; st[r][c4 + 1] = v[1];
      st[r][c4 + 2] = v[2]; st[r][c4 + 3] = v[3];
    }
  }
  __syncthreads();
  {
    const int nl0 = tid >> 3, c8 = (tid & 7) << 3;
#pragma unroll
    for (int i = 0; i < 2; ++i) {
      const int nl = nl0 + i * 32;
      bf16x8 o = {(__bf16)st[c8 + 0][nl], (__bf16)st[c8 + 1][nl],
                  (__bf16)st[c8 + 2][nl], (__bf16)st[c8 + 3][nl],
                  (__bf16)st[c8 + 4][nl], (__bf16)st[c8 + 5][nl],
                  (__bf16)st[c8 + 6][nl], (__bf16)st[c8 + 7][nl]};
      *(bf16x8*)&dst[(size_t)(n0 + nl) * Kpad + k0 + c8] = o;
    }
  }
}

// global conv tile space: [0, ACONV) layer tiles; [ACONV, ACONV+HCONV) head.
__device__ void conv_dispatch(int g, const ConvW& cw, char* sm) {
  if (g < ACONV) {
    const int l = g / LCONV;
    int b = g - l * LCONV;
    if (b < 768) {
      conv_tile(cw.Wqkv + (size_t)l * 1024 * 3072, cw.g_mha + (size_t)l * EDIM,
                cw.qkvT + (size_t)l * 3072 * 1024, 1024, 3072, 1024,
                b / 48, b % 48, sm);
    } else if (b < 1024) {
      int t = b - 768;
      conv_tile(cw.Wo + (size_t)l * 1024 * 1024, nullptr,
                cw.woT + (size_t)l * 1024 * 1024, 1024, 1024, 1024,
                t / 16, t % 16, sm);
    } else if (b < 1712) {
      int t = b - 1024;
      conv_tile(cw.W1 + (size_t)l * 1024 * DFFDIM, cw.g_ff + (size_t)l * EDIM,
                cw.w1T + (size_t)l * DPAD * 1024, 1024, DFFDIM, 1024,
                t / 43, t % 43, sm);
    } else if (b < 2400) {
      int t = b - 1712;
      conv_tile(cw.W3 + (size_t)l * 1024 * DFFDIM, cw.g_ff + (size_t)l * EDIM,
                cw.w3T + (size_t)l * DPAD * 1024, 1024, DFFDIM, 1024,
                t / 43, t % 43, sm);
    } else {
      int t = b - 2400;
      conv_tile(cw.W2w + (size_t)l * DFFDIM * 1024, nullptr,
                cw.w2T + (size_t)l * 1024 * DPAD, DFFDIM, 1024, DPAD,
                t / 16, t % 16, sm);
    }
  } else {
    const int t = g - ACONV;
    conv_tile(cw.Wout, cw.g_final, cw.WoutT, 1024, VOCAB, 1024,
              t >> 7, t & 127, sm);
  }
}

__global__ __launch_bounds__(256) void k_conv0(ConvW cw) {
  __shared__ __align__(16) char sm[16640];
  conv_dispatch(blockIdx.x, cw, sm);
}

// ================================================================ MFMA GEMM
// BM=128, BN in {64,128}; BK=64; 4 waves, wave tile 64 x BN/2.
// A/B bf16 via global_load_lds, counted-vmcnt double buffer. Flattened 1D
// grid; blocks past nx*ny*gz run carrier conv tiles.
// MODE: 0=qkv scatter  1=split-K f32 partial  2=SwiGLU dual  3=head
template <int BN, int MODE, int SC>
__global__ __launch_bounds__(256) void mm(
    const __bf16* __restrict__ A,
    const __bf16* __restrict__ B0w, const __bf16* __restrict__ B1w,
    const float* __restrict__ bias0, const float* __restrict__ bias1,
    const float* __restrict__ part,
    float* __restrict__ po, __bf16* __restrict__ ob,
    __bf16* __restrict__ qout, __bf16* __restrict__ kout, __bf16* __restrict__ vout,
    int N, int lda, int ldb, int Ktot,
    int nx, int ny, int gz, ConvW cw, int convoff) {
  constexpr int DUAL = (MODE == 2) ? 2 : 1;
  constexpr int FN = BN / 32;
  constexpr int BL = (BN == 128) ? 4 : 2 * DUAL;
  constexpr int ASZ = 32768;                 // [2][8][128][8] bf16
  constexpr int BSZ = DUAL * BN * 256;       // [2][DUAL][8][BN][8] bf16
  __shared__ __align__(16) char smem[ASZ + BSZ];
  const int bid = blockIdx.x;
  const int ncomp = nx * ny * gz;
  if (bid >= ncomp) {
    conv_dispatch(convoff + (bid - ncomp), cw, smem);
    return;
  }
  typedef __bf16 (*AsP)[8][128][8];
  typedef __bf16 (*BsP)[DUAL][8][BN][8];
  AsP As = (AsP)smem;
  BsP Bs = (BsP)(smem + ASZ);
  const int bz = bid / (nx * ny);
  const int r2 = bid - bz * nx * ny;
  const int by = r2 / nx, bx = r2 - by * nx;
  const int tid = threadIdx.x, lane = tid & 63, wave = tid >> 6;
  const int m0 = by << 7, n0 = bx * BN;
  const int wm0 = (wave >> 1) * 64, wn0 = (wave & 1) * (BN / 2);
  const int lr = lane & 15, kh = lane >> 4;

  const int ktiles = Ktot >> 6;
  const int nt0 = (ktiles + gz - 1) / gz;
  const int tbeg = bz * nt0;
  const int tend = (ktiles < tbeg + nt0) ? ktiles : (tbeg + nt0);
  const int nt = tend - tbeg;

  f32x4 acc[DUAL][4][FN];
#pragma unroll
  for (int d = 0; d < DUAL; ++d)
#pragma unroll
    for (int mi = 0; mi < 4; ++mi)
#pragma unroll
      for (int fn = 0; fn < FN; ++fn) acc[d][mi][fn] = (f32x4){0.f, 0.f, 0.f, 0.f};

  auto STAGE = [&](int buf, int t) {
    const int k0 = (tbeg + t) << 6;
#pragma unroll
    for (int i = 0; i < 4; ++i) {
      const int d = i * 256 + tid;
      gl_lds16(A + (size_t)(m0 + (d & 127)) * lda + k0 + (d >> 7) * 8,
               &As[buf][d >> 7][d & 127][0]);
    }
    if (BN == 128) {
#pragma unroll
      for (int i = 0; i < 4; ++i) {
        const int d = i * 256 + tid;
        gl_lds16(B0w + (size_t)(n0 + (d & 127)) * ldb + k0 + (d >> 7) * 8,
                 &Bs[buf][0][d >> 7][d & 127][0]);
      }
    } else {
#pragma unroll
      for (int i = 0; i < 2; ++i) {
        const int d = i * 256 + tid;
        gl_lds16(B0w + (size_t)(n0 + (d & 63)) * ldb + k0 + (d >> 6) * 8,
                 &Bs[buf][0][d >> 6][d & 63][0]);
      }
      if (DUAL == 2) {
#pragma unroll
        for (int i = 0; i < 2; ++i) {
          const int d = i * 256 + tid;
          gl_lds16(B1w + (size_t)(n0 + (d & 63)) * ldb + k0 + (d >> 6) * 8,
                   &Bs[buf][DUAL - 1][d >> 6][d & 63][0]);
        }
      }
    }
  };
  auto COMP = [&](int buf) {
#pragma unroll
    for (int ks = 0; ks < 2; ++ks) {
      const int kidx = ks * 4 + kh;
      bf16x8 af[4];
#pragma unroll
      for (int mi = 0; mi < 4; ++mi)
        af[mi] = *(const bf16x8*)&As[buf][kidx][wm0 + mi * 16 + lr][0];
#pragma unroll
      for (int d = 0; d < DUAL; ++d)
#pragma unroll
        for (int fn = 0; fn < FN; ++fn) {
          bf16x8 bfr = *(const bf16x8*)&Bs[buf][d][kidx][wn0 + fn * 16 + lr][0];
#pragma unroll
          for (int mi = 0; mi < 4; ++mi)
            acc[d][mi][fn] = MFMA(af[mi], bfr, acc[d][mi][fn]);
        }
    }
  };

  STAGE(0, 0);
  int cur = 0;
  for (int t = 0; t < nt - 1; ++t) {
    STAGE(cur ^ 1, t + 1);          // next tile stays in flight
    vmwait<4 + BL>();               // own tile-t loads retired
    __builtin_amdgcn_s_barrier();
    COMP(cur);
    __builtin_amdgcn_s_barrier();
    cur ^= 1;
  }
  vmwait<0>();
  __builtin_amdgcn_s_barrier();
  COMP(cur);

  float sc = 1.0f;
  if (SC) {
    __shared__ float smr[4];
    float s = part[tid] + part[tid + 256];
#pragma unroll
    for (int o = 32; o > 0; o >>= 1) s += __shfl_down(s, o);
    if ((tid & 63) == 0) smr[tid >> 6] = s;
    __syncthreads();
    sc = 1.0f / sqrtf((smr[0] + smr[1] + smr[2] + smr[3]) / (float)NELEM + EPSF);
  }

#pragma unroll
  for (int mi = 0; mi < 4; ++mi)
#pragma unroll
    for (int fn = 0; fn < FN; ++fn) {
      const int col = n0 + wn0 + fn * 16 + lr;
      if (MODE == 0) {
        const float bs = bias0[col];
        const int h = col / (3 * HDIM);
        const int rsel = (col >> 6) % 3;
        const int s2 = col & (HDIM - 1);
#pragma unroll
        for (int j = 0; j < 4; ++j) {
          const int row = m0 + wm0 + mi * 16 + (kh << 2) + j;
          const int b = row >> 9, t = row & (TSEQ - 1);
          const float v = acc[0][mi][fn][j] * sc + bs;
          if (rsel == 0)      qout[((size_t)(b * NHEAD + h) * TSEQ + t) * HDIM + s2] = (__bf16)v;
          else if (rsel == 1) kout[((size_t)(b * NHEAD + h) * TSEQ + t) * HDIM + s2] = (__bf16)v;
          else                vout[((size_t)(b * NHEAD + h) * HDIM + s2) * TSEQ + t] = (__bf16)v;
        }
      } else if (MODE == 1) {
        float* pz = po + (size_t)bz * NELEM;
#pragma unroll
        for (int j = 0; j < 4; ++j) {
          const int row = m0 + wm0 + mi * 16 + (kh << 2) + j;
          pz[(size_t)row * EDIM + col] = acc[0][mi][fn][j];
        }
      } else if (MODE == 2) {
        const bool ok = col < N;
        const float bb1 = ok ? bias0[col] : 0.f;
        const float bb3 = ok ? bias1[col] : 0.f;
#pragma unroll
        for (int j = 0; j < 4; ++j) {
          const int row = m0 + wm0 + mi * 16 + (kh << 2) + j;
          float v = 0.f;
          if (ok) {
            const float a1v = acc[0][mi][fn][j] * sc + bb1;
            const float a3v = acc[DUAL - 1][mi][fn][j] * sc + bb3;
            v = a1v * (1.0f / (1.0f + __expf(-a1v))) * a3v;
          }
          ob[(size_t)row * DPAD + col] = (__bf16)v;
        }
      } else {
        if (col < N) {
          const float bs = bias0[col];
#pragma unroll
          for (int j = 0; j < 4; ++j) {
            const int row = m0 + wm0 + mi * 16 + (kh << 2) + j;
            po[(size_t)row * N + col] = acc[0][mi][fn][j] * sc + bs;
          }
        }
      }
    }
}

// ------------------------------------------------- flash attention (bf16 in)
// 32-row Q tiles; 512 compute blocks + carrier conv blocks. dbuf K/V,
// counted vmcnt, defer-max THR=8.
__global__ __launch_bounds__(256) void k_flash(const __bf16* __restrict__ qbuf,
                                               const __bf16* __restrict__ kbuf,
                                               const __bf16* __restrict__ vbufT,
                                               __bf16* __restrict__ y2,
                                               ConvW cw, int convoff) {
  __shared__ __align__(16) char smem[41472];
  const int bid = blockIdx.x;
  if (bid >= 512) {
    conv_dispatch(convoff + (bid - 512), cw, smem);
    return;
  }
  const int qt = bid & 15, bh = bid >> 4;
  const int b = bh >> 4, h = bh & 15;
  const int m0 = qt << 5;
  const __bf16* qp = qbuf  + (size_t)bh * TSEQ * HDIM;
  const __bf16* kp = kbuf  + (size_t)bh * TSEQ * HDIM;
  const __bf16* vp = vbufT + (size_t)bh * HDIM * TSEQ;   // [d][t]
  __bf16 (*Qs)[32][8]    = (__bf16 (*)[32][8])smem;                    // 4KB
  __bf16 (*Ks)[8][64][8] = (__bf16 (*)[8][64][8])(smem + 4096);        // 16KB
  __bf16 (*Vs)[8][64][8] = (__bf16 (*)[8][64][8])(smem + 20480);       // 16KB
  __bf16 (*Ps)[32][8]    = (__bf16 (*)[32][8])(smem + 36864);          // 4KB
  float* wmaxp = (float*)(smem + 40960);                               // [2][32]
  float* wsump = wmaxp + 64;                                           // [2][32]
  const int tid = threadIdx.x, lane = tid & 63, wave = tid >> 6;
  const int wm = (wave >> 1) << 4, wn = (wave & 1) << 5;
  const int lr = lane & 15, kh = lane >> 4;

  auto STAGE_KV = [&](int kt2, int buf) {
    const int n0s = kt2 << 6;
#pragma unroll
    for (int i = 0; i < 2; ++i) {
      const int d = i * 256 + tid;
      const int kb2 = d >> 6, row = d & 63;
      gl_lds16(kp + (size_t)(n0s + row) * HDIM + kb2 * 8, &Ks[buf][kb2][row][0]);
      gl_lds16(vp + (size_t)row * TSEQ + n0s + kb2 * 8, &Vs[buf][kb2][row][0]);
    }
  };

  gl_lds16(qp + (size_t)(m0 + (tid & 31)) * HDIM + (tid >> 5) * 8,
           &Qs[tid >> 5][tid & 31][0]);
  STAGE_KV(0, 0);

  float m_[4], l_[4];
#pragma unroll
  for (int j = 0; j < 4; ++j) { m_[j] = NEGBIG; l_[j] = 0.f; }
  f32x4 o0 = {0, 0, 0, 0}, o1 = {0, 0, 0, 0};

  const int ktmax = qt >> 1;
  int cur = 0;
  for (int kt = 0; kt <= ktmax; ++kt) {
    const int n0 = kt << 6;
    if (kt < ktmax) {
      STAGE_KV(kt + 1, cur ^ 1);
      vmwait<4>();
    } else {
      vmwait<0>();
    }
    __builtin_amdgcn_s_barrier();

    f32x4 s0 = {0, 0, 0, 0}, s1 = {0, 0, 0, 0};
#pragma unroll
    for (int ks = 0; ks < 2; ++ks) {
      const int kidx = ks * 4 + kh;
      bf16x8 a  = *(const bf16x8*)&Qs[kidx][wm + lr][0];
      bf16x8 b0 = *(const bf16x8*)&Ks[cur][kidx][wn + lr][0];
      bf16x8 b1 = *(const bf16x8*)&Ks[cur][kidx][wn + 16 + lr][0];
      s0 = MFMA(a, b0, s0); s1 = MFMA(a, b1, s1);
    }
    float pv0[4], pv1[4];
#pragma unroll
    for (int j = 0; j < 4; ++j) {
      const int grow = m0 + wm + (kh << 2) + j;
      float t0 = s0[j] * SCALEF; if (n0 + wn + lr > grow)      t0 = NEGBIG;
      float t1 = s1[j] * SCALEF; if (n0 + wn + 16 + lr > grow) t1 = NEGBIG;
      pv0[j] = t0; pv1[j] = t1;
      float v = fmaxf(t0, t1);
      v = fmaxf(v, __shfl_xor(v, 1)); v = fmaxf(v, __shfl_xor(v, 2));
      v = fmaxf(v, __shfl_xor(v, 4)); v = fmaxf(v, __shfl_xor(v, 8));
      wmaxp[(wave & 1) * 32 + wm + (kh << 2) + j] = v;
    }
    lgkm_barrier();

    float tmax[4]; bool need = false;
#pragma unroll
    for (int j = 0; j < 4; ++j) {
      const int rl = wm + (kh << 2) + j;
      tmax[j] = fmaxf(wmaxp[rl], wmaxp[32 + rl]);
      need |= (tmax[j] > m_[j] + 8.f);
    }
    if (__ballot(need)) {
#pragma unroll
      for (int j = 0; j < 4; ++j) {
        const float mn = fmaxf(m_[j], tmax[j]);
        const float al = __expf(m_[j] - mn);
        m_[j] = mn; l_[j] *= al; o0[j] *= al; o1[j] *= al;
      }
    }
#pragma unroll
    for (int j = 0; j < 4; ++j) {
      const float p0 = __expf(pv0[j] - m_[j]);
      const float p1 = __expf(pv1[j] - m_[j]);
      float rs = p0 + p1;
      rs += __shfl_xor(rs, 1); rs += __shfl_xor(rs, 2);
      rs += __shfl_xor(rs, 4); rs += __shfl_xor(rs, 8);
      const int rl = wm + (kh << 2) + j;
      wsump[(wave & 1) * 32 + rl] = rs;
      const int pc0 = wn + lr, pc1 = wn + 16 + lr;
      Ps[pc0 >> 3][rl][pc0 & 7] = (__bf16)p0;
      Ps[pc1 >> 3][rl][pc1 & 7] = (__bf16)p1;
    }
    lgkm_barrier();

#pragma unroll
    for (int j = 0; j < 4; ++j) {
      const int rl = wm + (kh << 2) + j;
      l_[j] += wsump[rl] + wsump[32 + rl];
    }
#pragma unroll
    for (int ks = 0; ks < 2; ++ks) {
      const int kidx = ks * 4 + kh;
      bf16x8 a  = *(const bf16x8*)&Ps[kidx][wm + lr][0];
      bf16x8 b0 = *(const bf16x8*)&Vs[cur][kidx][wn + lr][0];
      bf16x8 b1 = *(const bf16x8*)&Vs[cur][kidx][wn + 16 + lr][0];
      o0 = MFMA(a, b0, o0); o1 = MFMA(a, b1, o1);
    }
    __builtin_amdgcn_s_barrier();
    cur ^= 1;
  }

#pragma unroll
  for (int j = 0; j < 4; ++j) {
    const int row = m0 + wm + (kh << 2) + j;
    const float inv = 1.0f / l_[j];
    y2[((size_t)(b * TSEQ) + row) * EDIM + h * HDIM + wn + lr]      = (__bf16)(o0[j] * inv);
    y2[((size_t)(b * TSEQ) + row) * EDIM + h * HDIM + wn + 16 + lr] = (__bf16)(o1[j] * inv);
  }
}

// ---------------------------------------------------------------- launcher
extern "C" void kernel_launch(void* const* d_in, const int* in_sizes, int n_in,
                              void* d_out, int out_size, void* d_ws, size_t ws_size,
                              hipStream_t stream) {
  const int*   tokens  = (const int*)d_in[0];
  const float* emb     = (const float*)d_in[1];
  const float* Wqkv    = (const float*)d_in[2];
  const float* bqkv    = (const float*)d_in[3];
  const float* Wo      = (const float*)d_in[4];
  const float* bo      = (const float*)d_in[5];
  const float* W1      = (const float*)d_in[6];
  const float* b1      = (const float*)d_in[7];
  const float* W3      = (const float*)d_in[8];
  const float* b3      = (const float*)d_in[9];
  const float* W2w     = (const float*)d_in[10];
  const float* b2      = (const float*)d_in[11];
  const float* g_mha   = (const float*)d_in[12];
  const float* g_ff    = (const float*)d_in[13];
  const float* g_final = (const float*)d_in[14];
  const float* Wout    = (const float*)d_in[15];
  const float* bout    = (const float*)d_in[16];
  float* out = (float*)d_out;

  char* base = (char*)d_ws;
  size_t off = 0;
  auto alloc = [&](size_t bytes) { char* p = base + off; off = (off + bytes + 255) & ~(size_t)255; return p; };
  float*  x    = (float*)alloc(4u << 20);
  float*  part = (float*)alloc(4096);
  __bf16* ybf  = (__bf16*)alloc(2u << 20);
  __bf16* qbf  = (__bf16*)alloc(2u << 20);
  __bf16* kbf  = (__bf16*)alloc(2u << 20);
  __bf16* vbT  = (__bf16*)alloc(2u << 20);
  __bf16* y2bf = (__bf16*)alloc(2u << 20);
  __bf16* ubf  = (__bf16*)alloc((size_t)MTOK * DPAD * 2);
  float*  pbuf = (float*)alloc((size_t)4 * NELEM * 4);
  __bf16* WoutT = (__bf16*)alloc((size_t)8192 * 1024 * 2);
  __bf16* qkvT = (__bf16*)alloc((size_t)NLAYER * 3072 * 1024 * 2);
  __bf16* woT  = (__bf16*)alloc((size_t)NLAYER * 1024 * 1024 * 2);
  __bf16* w1T  = (__bf16*)alloc((size_t)NLAYER * DPAD * 1024 * 2);
  __bf16* w3T  = (__bf16*)alloc((size_t)NLAYER * DPAD * 1024 * 2);
  __bf16* w2T  = (__bf16*)alloc((size_t)NLAYER * 1024 * DPAD * 2);

  ConvW cw;
  cw.Wqkv = Wqkv; cw.Wo = Wo; cw.W1 = W1; cw.W3 = W3; cw.W2w = W2w;
  cw.g_mha = g_mha; cw.g_ff = g_ff; cw.Wout = Wout; cw.g_final = g_final;
  cw.qkvT = qkvT; cw.woT = woT; cw.w1T = w1T; cw.w3T = w3T; cw.w2T = w2T;
  cw.WoutT = WoutT;

  k_embed<<<MTOK, 256, 0, stream>>>(tokens, emb, x);
  k_conv0<<<LCONV, 256, 0, stream>>>(cw);              // layer-0 weights only
  k_red1f<0><<<RGRID, 256, 0, stream>>>(x, nullptr, nullptr, part, ybf);

  for (int l = 0; l < NLAYER; ++l) {
    // carriers convert layer l+1 (or the head when l==23)
    const int co = (l + 1 < NLAYER) ? (l + 1) * LCONV : ACONV;
    const int cn = (l + 1 < NLAYER) ? 772 : 512;       // 4 carrier groups/layer
    // --- MHA ---
    mm<64, 0, 1><<<384 + cn, 256, 0, stream>>>(
        ybf, qkvT + (size_t)l * 3072 * 1024, nullptr,
        bqkv + (size_t)l * 3 * EDIM, nullptr, part,
        nullptr, nullptr, qbf, kbf, vbT, 3072, 1024, 1024, 1024,
        48, 8, 1, cw, co);
    k_flash<<<512 + cn, 256, 0, stream>>>(qbf, kbf, vbT, y2bf, cw, co + cn);
    mm<64, 1, 0><<<512, 256, 0, stream>>>(
        y2bf, woT + (size_t)l * 1024 * 1024, nullptr,
        nullptr, nullptr, nullptr,
        pbuf, nullptr, nullptr, nullptr, nullptr, 1024, 1024, 1024, 1024,
        16, 8, 4, cw, 0);
    // --- SwiGLU FFN ---
    k_red1f<4><<<RGRID, 256, 0, stream>>>(x, pbuf, bo + (size_t)l * EDIM, part, ybf);
    mm<64, 2, 1><<<344 + cn, 256, 0, stream>>>(
        ybf, w1T + (size_t)l * DPAD * 1024, w3T + (size_t)l * DPAD * 1024,
        b1 + (size_t)l * DFFDIM, b3 + (size_t)l * DFFDIM, part,
        nullptr, ubf, nullptr, nullptr, nullptr, DFFDIM, 1024, 1024, 1024,
        43, 8, 1, cw, co + 2 * cn);
    mm<64, 1, 0><<<512 + cn, 256, 0, stream>>>(
        ubf, w2T + (size_t)l * 1024 * DPAD, nullptr,
        nullptr, nullptr, nullptr,
        pbuf, nullptr, nullptr, nullptr, nullptr, 1024, DPAD, DPAD, DPAD,
        16, 8, 4, cw, co + 3 * cn);
    // fold w2 partials + b2; emits next layer's (or head's) ybf/part
    k_red1f<4><<<RGRID, 256, 0, stream>>>(x, pbuf, b2 + (size_t)l * EDIM, part, ybf);
  }

  // --- vocab head ---
  mm<128, 3, 1><<<512, 256, 0, stream>>>(
      ybf, WoutT, nullptr, bout, nullptr, part,
      out, nullptr, nullptr, nullptr, nullptr, VOCAB, 1024, 1024, 1024,
      64, 8, 1, cw, 0);
}

// Round 22
// 3487.881 us; speedup vs baseline: 2.1020x; 1.0009x over previous
//
#include <hip/hip_runtime.h>
#include <hip/hip_bf16.h>
#include <math.h>

#define EDIM   1024
#define TSEQ   512
#define NBATCH 2
#define NHEAD  16
#define HDIM   64
#define NLAYER 24
#define VOCAB  8124
#define DFFDIM 2730
#define DPAD   2752              // 43*64 padded SwiGLU width
#define MTOK   (NBATCH*TSEQ)     // 1024
#define NELEM  (MTOK*EDIM)
#define EPSF   1e-5f
#define SCALEF (1.0f/32.0f)
#define NEGBIG (-1e30f)
#define LCONV  3088              // conv tiles per layer
#define ACONV  (NLAYER*LCONV)    // 74112, then head tiles follow
#define HCONV  2048
#define RGRID  512               // red1f blocks (2/CU)

typedef __bf16 bf16x8 __attribute__((ext_vector_type(8)));
typedef __bf16 bf16x4 __attribute__((ext_vector_type(4)));
typedef float  f32x4  __attribute__((ext_vector_type(4)));

#define MFMA(a, b, c) __builtin_amdgcn_mfma_f32_16x16x32_bf16((a), (b), (c), 0, 0, 0)

__device__ __forceinline__ void gl_lds16(const __bf16* g, __bf16* l) {
  __builtin_amdgcn_global_load_lds(
      (const __attribute__((address_space(1))) void*)g,
      (__attribute__((address_space(3))) void*)l, 16, 0, 0);
}
template <int N> __device__ __forceinline__ void vmwait() {
  asm volatile("s_waitcnt vmcnt(%0)" :: "n"(N) : "memory");
}
__device__ __forceinline__ void lgkm_barrier() {
  asm volatile("s_waitcnt lgkmcnt(0)" ::: "memory");
  __builtin_amdgcn_s_barrier();
}

// ---------------- weight pointers bundle (for carrier conv blocks)
struct ConvW {
  const float *Wqkv, *Wo, *W1, *W3, *W2w, *g_mha, *g_ff, *Wout, *g_final;
  __bf16 *qkvT, *woT, *w1T, *w3T, *w2T, *WoutT;
};

// ---------------------------------------------------------------- embedding+PE
__global__ __launch_bounds__(256) void k_embed(const int* __restrict__ tok,
                                               const float* __restrict__ emb,
                                               float* __restrict__ x) {
  const int bt = blockIdx.x;
  const int t  = bt & (TSEQ - 1);
  const int tk = tok[bt];
  const float* er = emb + (size_t)tk * EDIM;
  float* xr = x + (size_t)bt * EDIM;
  for (int e = threadIdx.x * 4; e < EDIM; e += 256 * 4) {
    float4 v = *(const float4*)(er + e);
    float vv[4] = {v.x, v.y, v.z, v.w};
    float ou[4];
#pragma unroll
    for (int j = 0; j < 4; ++j) {
      int ee = e + j;
      int i2 = ee & ~1;
      float freq = expf(-(float)i2 * (9.210340371976184f / 1024.0f));
      float ang  = (float)t * freq;
      ou[j] = vv[j] + ((ee & 1) ? cosf(ang) : sinf(ang));
    }
    *(float4*)(xr + e) = make_float4(ou[0], ou[1], ou[2], ou[3]);
  }
}

// ----------------- RMS reduce (+fold NP partials) + emit bf16(x). RGRID blocks.
template <int NP>
__global__ __launch_bounds__(256) void k_red1f(float* __restrict__ x,
                                               const float* __restrict__ pb,
                                               const float* __restrict__ bias,
                                               float* __restrict__ part,
                                               __bf16* __restrict__ ybf) {
  const int tid = threadIdx.x;
  float s = 0.f;
  for (int i = (blockIdx.x * 256 + tid) * 4; i < NELEM; i += RGRID * 256 * 4) {
    float4 v = *(const float4*)(x + i);
    if constexpr (NP > 0) {
      f32x4 a[NP];
#pragma unroll
      for (int z = 0; z < NP; ++z)
        a[z] = __builtin_nontemporal_load((const f32x4*)(pb + (size_t)z * NELEM + i));
      float4 c = *(const float4*)(bias + (i & (EDIM - 1)));
#pragma unroll
      for (int z = 0; z < NP; ++z) {
        v.x += a[z][0]; v.y += a[z][1]; v.z += a[z][2]; v.w += a[z][3];
      }
      v.x += c.x; v.y += c.y; v.z += c.z; v.w += c.w;
      *(float4*)(x + i) = v;
    }
    bf16x4 o = {(__bf16)v.x, (__bf16)v.y, (__bf16)v.z, (__bf16)v.w};
    *(bf16x4*)(ybf + i) = o;
    s += v.x * v.x + v.y * v.y + v.z * v.z + v.w * v.w;
  }
#pragma unroll
  for (int o = 32; o > 0; o >>= 1) s += __shfl_down(s, o);
  __shared__ float sm[4];
  if ((tid & 63) == 0) sm[tid >> 6] = s;
  __syncthreads();
  if (tid == 0) part[blockIdx.x] = sm[0] + sm[1] + sm[2] + sm[3];
}

// ------------------------------------------------- weight convert + transpose
__device__ void conv_tile(const float* __restrict__ src,
                          const float* __restrict__ gk,
                          __bf16* __restrict__ dst,
                          int K, int N, int Kpad, int tk, int tn, char* smv) {
  float (*st)[65] = (float (*)[65])smv;   // 64 x 65 f32 = 16,640 B
  const int k0 = tk << 6, n0 = tn << 6;
  const int tid = threadIdx.x;
  {
    const int r0 = tid >> 4, c4 = (tid & 15) << 2;
#pragma unroll
    for (int i = 0; i < 4; ++i) {
      const int r = r0 + i * 16;
      const int k = k0 + r;
      f32x4 v = {0.f, 0.f, 0.f, 0.f};
      if (k < K) {
        const float* sp = src + (size_t)k * N + n0 + c4;
        if (n0 + c4 + 3 < N) v = __builtin_nontemporal_load((const f32x4*)sp);
        else {
          if (n0 + c4 + 0 < N) v[0] = sp[0];
          if (n0 + c4 + 1 < N) v[1] = sp[1];
          if (n0 + c4 + 2 < N) v[2] = sp[2];
          if (n0 + c4 + 3 < N) v[3] = sp[3];
        }
        if (gk) {
          const float gv = gk[k];
          v[0] *= gv; v[1] *= gv; v[2] *= gv; v[3] *= gv;
        }
      }
      st[r][c4 + 0] = v[0]; st[r][c4 + 1] = v[1];
      st[r][c4 + 2] = v[2]; st[r][c4 + 3] = v[3];
    }
  }
  __syncthreads();
  {
    const int nl0 = tid >> 3, c8 = (tid & 7) << 3;
#pragma unroll
    for (int i = 0; i < 2; ++i) {
      const int nl = nl0 + i * 32;
      bf16x8 o = {(__bf16)st[c8 + 0][nl], (__bf16)st[c8 + 1][nl],
                  (__bf16)st[c8 + 2][nl], (__bf16)st[c8 + 3][nl],
                  (__bf16)st[c8 + 4][nl], (__bf16)st[c8 + 5][nl],
                  (__bf16)st[c8 + 6][nl], (__bf16)st[c8 + 7][nl]};
      *(bf16x8*)&dst[(size_t)(n0 + nl) * Kpad + k0 + c8] = o;
    }
  }
}

// global conv tile space: [0, ACONV) layer tiles; [ACONV, ACONV+HCONV) head.
__device__ void conv_dispatch(int g, const ConvW& cw, char* sm) {
  if (g < ACONV) {
    const int l = g / LCONV;
    int b = g - l * LCONV;
    if (b < 768) {
      conv_tile(cw.Wqkv + (size_t)l * 1024 * 3072, cw.g_mha + (size_t)l * EDIM,
                cw.qkvT + (size_t)l * 3072 * 1024, 1024, 3072, 1024,
                b / 48, b % 48, sm);
    } else if (b < 1024) {
      int t = b - 768;
      conv_tile(cw.Wo + (size_t)l * 1024 * 1024, nullptr,
                cw.woT + (size_t)l * 1024 * 1024, 1024, 1024, 1024,
                t / 16, t % 16, sm);
    } else if (b < 1712) {
      int t = b - 1024;
      conv_tile(cw.W1 + (size_t)l * 1024 * DFFDIM, cw.g_ff + (size_t)l * EDIM,
                cw.w1T + (size_t)l * DPAD * 1024, 1024, DFFDIM, 1024,
                t / 43, t % 43, sm);
    } else if (b < 2400) {
      int t = b - 1712;
      conv_tile(cw.W3 + (size_t)l * 1024 * DFFDIM, cw.g_ff + (size_t)l * EDIM,
                cw.w3T + (size_t)l * DPAD * 1024, 1024, DFFDIM, 1024,
                t / 43, t % 43, sm);
    } else {
      int t = b - 2400;
      conv_tile(cw.W2w + (size_t)l * DFFDIM * 1024, nullptr,
                cw.w2T + (size_t)l * 1024 * DPAD, DFFDIM, 1024, DPAD,
                t / 16, t % 16, sm);
    }
  } else {
    const int t = g - ACONV;
    conv_tile(cw.Wout, cw.g_final, cw.WoutT, 1024, VOCAB, 1024,
              t >> 7, t & 127, sm);
  }
}

__global__ __launch_bounds__(256) void k_conv0(ConvW cw) {
  __shared__ __align__(16) char sm[16640];
  conv_dispatch(blockIdx.x, cw, sm);
}

// ================================================================ MFMA GEMM
// BM=128, BN in {64,128}; BK=64; 4 waves, wave tile 64 x BN/2.
// A/B bf16 via global_load_lds, counted-vmcnt double buffer. Flattened 1D
// grid; blocks past nx*ny*gz run carrier conv tiles.
// MODE: 0=qkv scatter  1=split-K f32 partial  2=SwiGLU dual  3=head
template <int BN, int MODE, int SC>
__global__ __launch_bounds__(256) void mm(
    const __bf16* __restrict__ A,
    const __bf16* __restrict__ B0w, const __bf16* __restrict__ B1w,
    const float* __restrict__ bias0, const float* __restrict__ bias1,
    const float* __restrict__ part,
    float* __restrict__ po, __bf16* __restrict__ ob,
    __bf16* __restrict__ qout, __bf16* __restrict__ kout, __bf16* __restrict__ vout,
    int N, int lda, int ldb, int Ktot,
    int nx, int ny, int gz, ConvW cw, int convoff) {
  constexpr int DUAL = (MODE == 2) ? 2 : 1;
  constexpr int FN = BN / 32;
  constexpr int BL = (BN == 128) ? 4 : 2 * DUAL;
  constexpr int ASZ = 32768;                 // [2][8][128][8] bf16
  constexpr int BSZ = DUAL * BN * 256;       // [2][DUAL][8][BN][8] bf16
  __shared__ __align__(16) char smem[ASZ + BSZ];
  const int bid = blockIdx.x;
  const int ncomp = nx * ny * gz;
  if (bid >= ncomp) {
    conv_dispatch(convoff + (bid - ncomp), cw, smem);
    return;
  }
  typedef __bf16 (*AsP)[8][128][8];
  typedef __bf16 (*BsP)[DUAL][8][BN][8];
  AsP As = (AsP)smem;
  BsP Bs = (BsP)(smem + ASZ);
  const int bz = bid / (nx * ny);
  const int r2 = bid - bz * nx * ny;
  const int by = r2 / nx, bx = r2 - by * nx;
  const int tid = threadIdx.x, lane = tid & 63, wave = tid >> 6;
  const int m0 = by << 7, n0 = bx * BN;
  const int wm0 = (wave >> 1) * 64, wn0 = (wave & 1) * (BN / 2);
  const int lr = lane & 15, kh = lane >> 4;

  const int ktiles = Ktot >> 6;
  const int nt0 = (ktiles + gz - 1) / gz;
  const int tbeg = bz * nt0;
  const int tend = (ktiles < tbeg + nt0) ? ktiles : (tbeg + nt0);
  const int nt = tend - tbeg;

  f32x4 acc[DUAL][4][FN];
#pragma unroll
  for (int d = 0; d < DUAL; ++d)
#pragma unroll
    for (int mi = 0; mi < 4; ++mi)
#pragma unroll
      for (int fn = 0; fn < FN; ++fn) acc[d][mi][fn] = (f32x4){0.f, 0.f, 0.f, 0.f};

  auto STAGE = [&](int buf, int t) {
    const int k0 = (tbeg + t) << 6;
#pragma unroll
    for (int i = 0; i < 4; ++i) {
      const int d = i * 256 + tid;
      gl_lds16(A + (size_t)(m0 + (d & 127)) * lda + k0 + (d >> 7) * 8,
               &As[buf][d >> 7][d & 127][0]);
    }
    if (BN == 128) {
#pragma unroll
      for (int i = 0; i < 4; ++i) {
        const int d = i * 256 + tid;
        gl_lds16(B0w + (size_t)(n0 + (d & 127)) * ldb + k0 + (d >> 7) * 8,
                 &Bs[buf][0][d >> 7][d & 127][0]);
      }
    } else {
#pragma unroll
      for (int i = 0; i < 2; ++i) {
        const int d = i * 256 + tid;
        gl_lds16(B0w + (size_t)(n0 + (d & 63)) * ldb + k0 + (d >> 6) * 8,
                 &Bs[buf][0][d >> 6][d & 63][0]);
      }
      if (DUAL == 2) {
#pragma unroll
        for (int i = 0; i < 2; ++i) {
          const int d = i * 256 + tid;
          gl_lds16(B1w + (size_t)(n0 + (d & 63)) * ldb + k0 + (d >> 6) * 8,
                   &Bs[buf][DUAL - 1][d >> 6][d & 63][0]);
        }
      }
    }
  };
  auto COMP = [&](int buf) {
#pragma unroll
    for (int ks = 0; ks < 2; ++ks) {
      const int kidx = ks * 4 + kh;
      bf16x8 af[4];
#pragma unroll
      for (int mi = 0; mi < 4; ++mi)
        af[mi] = *(const bf16x8*)&As[buf][kidx][wm0 + mi * 16 + lr][0];
#pragma unroll
      for (int d = 0; d < DUAL; ++d)
#pragma unroll
        for (int fn = 0; fn < FN; ++fn) {
          bf16x8 bfr = *(const bf16x8*)&Bs[buf][d][kidx][wn0 + fn * 16 + lr][0];
#pragma unroll
          for (int mi = 0; mi < 4; ++mi)
            acc[d][mi][fn] = MFMA(af[mi], bfr, acc[d][mi][fn]);
        }
    }
  };

  STAGE(0, 0);
  int cur = 0;
  for (int t = 0; t < nt - 1; ++t) {
    STAGE(cur ^ 1, t + 1);          // next tile stays in flight
    vmwait<4 + BL>();               // own tile-t loads retired
    __builtin_amdgcn_s_barrier();
    COMP(cur);
    __builtin_amdgcn_s_barrier();
    cur ^= 1;
  }
  vmwait<0>();
  __builtin_amdgcn_s_barrier();
  COMP(cur);

  float sc = 1.0f;
  if (SC) {
    __shared__ float smr[4];
    float s = part[tid] + part[tid + 256];
#pragma unroll
    for (int o = 32; o > 0; o >>= 1) s += __shfl_down(s, o);
    if ((tid & 63) == 0) smr[tid >> 6] = s;
    __syncthreads();
    sc = 1.0f / sqrtf((smr[0] + smr[1] + smr[2] + smr[3]) / (float)NELEM + EPSF);
  }

#pragma unroll
  for (int mi = 0; mi < 4; ++mi)
#pragma unroll
    for (int fn = 0; fn < FN; ++fn) {
      const int col = n0 + wn0 + fn * 16 + lr;
      if (MODE == 0) {
        const float bs = bias0[col];
        const int h = col / (3 * HDIM);
        const int rsel = (col >> 6) % 3;
        const int s2 = col & (HDIM - 1);
#pragma unroll
        for (int j = 0; j < 4; ++j) {
          const int row = m0 + wm0 + mi * 16 + (kh << 2) + j;
          const int b = row >> 9, t = row & (TSEQ - 1);
          const float v = acc[0][mi][fn][j] * sc + bs;
          if (rsel == 0)      qout[((size_t)(b * NHEAD + h) * TSEQ + t) * HDIM + s2] = (__bf16)v;
          else if (rsel == 1) kout[((size_t)(b * NHEAD + h) * TSEQ + t) * HDIM + s2] = (__bf16)v;
          else                vout[((size_t)(b * NHEAD + h) * HDIM + s2) * TSEQ + t] = (__bf16)v;
        }
      } else if (MODE == 1) {
        float* pz = po + (size_t)bz * NELEM;
#pragma unroll
        for (int j = 0; j < 4; ++j) {
          const int row = m0 + wm0 + mi * 16 + (kh << 2) + j;
          pz[(size_t)row * EDIM + col] = acc[0][mi][fn][j];
        }
      } else if (MODE == 2) {
        const bool ok = col < N;
        const float bb1 = ok ? bias0[col] : 0.f;
        const float bb3 = ok ? bias1[col] : 0.f;
#pragma unroll
        for (int j = 0; j < 4; ++j) {
          const int row = m0 + wm0 + mi * 16 + (kh << 2) + j;
          float v = 0.f;
          if (ok) {
            const float a1v = acc[0][mi][fn][j] * sc + bb1;
            const float a3v = acc[DUAL - 1][mi][fn][j] * sc + bb3;
            v = a1v * (1.0f / (1.0f + __expf(-a1v))) * a3v;
          }
          ob[(size_t)row * DPAD + col] = (__bf16)v;
        }
      } else {
        if (col < N) {
          const float bs = bias0[col];
#pragma unroll
          for (int j = 0; j < 4; ++j) {
            const int row = m0 + wm0 + mi * 16 + (kh << 2) + j;
            po[(size_t)row * N + col] = acc[0][mi][fn][j] * sc + bs;
          }
        }
      }
    }
}

// ------------------------------------------------- flash attention (bf16 in)
// 32-row Q tiles; 512 compute blocks + carrier conv blocks. dbuf K/V,
// counted vmcnt, defer-max THR=8. Longest-job-first: qt reversed so 8-iter
// blocks launch before 1-iter blocks within each stripe (shorter tail).
__global__ __launch_bounds__(256) void k_flash(const __bf16* __restrict__ qbuf,
                                               const __bf16* __restrict__ kbuf,
                                               const __bf16* __restrict__ vbufT,
                                               __bf16* __restrict__ y2,
                                               ConvW cw, int convoff) {
  __shared__ __align__(16) char smem[41472];
  const int bid = blockIdx.x;
  if (bid >= 512) {
    conv_dispatch(convoff + (bid - 512), cw, smem);
    return;
  }
  const int qt = 15 - (bid & 15), bh = bid >> 4;   // longest-first
  const int b = bh >> 4, h = bh & 15;
  const int m0 = qt << 5;
  const __bf16* qp = qbuf  + (size_t)bh * TSEQ * HDIM;
  const __bf16* kp = kbuf  + (size_t)bh * TSEQ * HDIM;
  const __bf16* vp = vbufT + (size_t)bh * HDIM * TSEQ;   // [d][t]
  __bf16 (*Qs)[32][8]    = (__bf16 (*)[32][8])smem;                    // 4KB
  __bf16 (*Ks)[8][64][8] = (__bf16 (*)[8][64][8])(smem + 4096);        // 16KB
  __bf16 (*Vs)[8][64][8] = (__bf16 (*)[8][64][8])(smem + 20480);       // 16KB
  __bf16 (*Ps)[32][8]    = (__bf16 (*)[32][8])(smem + 36864);          // 4KB
  float* wmaxp = (float*)(smem + 40960);                               // [2][32]
  float* wsump = wmaxp + 64;                                           // [2][32]
  const int tid = threadIdx.x, lane = tid & 63, wave = tid >> 6;
  const int wm = (wave >> 1) << 4, wn = (wave & 1) << 5;
  const int lr = lane & 15, kh = lane >> 4;

  auto STAGE_KV = [&](int kt2, int buf) {
    const int n0s = kt2 << 6;
#pragma unroll
    for (int i = 0; i < 2; ++i) {
      const int d = i * 256 + tid;
      const int kb2 = d >> 6, row = d & 63;
      gl_lds16(kp + (size_t)(n0s + row) * HDIM + kb2 * 8, &Ks[buf][kb2][row][0]);
      gl_lds16(vp + (size_t)row * TSEQ + n0s + kb2 * 8, &Vs[buf][kb2][row][0]);
    }
  };

  gl_lds16(qp + (size_t)(m0 + (tid & 31)) * HDIM + (tid >> 5) * 8,
           &Qs[tid >> 5][tid & 31][0]);
  STAGE_KV(0, 0);

  float m_[4], l_[4];
#pragma unroll
  for (int j = 0; j < 4; ++j) { m_[j] = NEGBIG; l_[j] = 0.f; }
  f32x4 o0 = {0, 0, 0, 0}, o1 = {0, 0, 0, 0};

  const int ktmax = qt >> 1;
  int cur = 0;
  for (int kt = 0; kt <= ktmax; ++kt) {
    const int n0 = kt << 6;
    if (kt < ktmax) {
      STAGE_KV(kt + 1, cur ^ 1);
      vmwait<4>();
    } else {
      vmwait<0>();
    }
    __builtin_amdgcn_s_barrier();

    f32x4 s0 = {0, 0, 0, 0}, s1 = {0, 0, 0, 0};
#pragma unroll
    for (int ks = 0; ks < 2; ++ks) {
      const int kidx = ks * 4 + kh;
      bf16x8 a  = *(const bf16x8*)&Qs[kidx][wm + lr][0];
      bf16x8 b0 = *(const bf16x8*)&Ks[cur][kidx][wn + lr][0];
      bf16x8 b1 = *(const bf16x8*)&Ks[cur][kidx][wn + 16 + lr][0];
      s0 = MFMA(a, b0, s0); s1 = MFMA(a, b1, s1);
    }
    float pv0[4], pv1[4];
#pragma unroll
    for (int j = 0; j < 4; ++j) {
      const int grow = m0 + wm + (kh << 2) + j;
      float t0 = s0[j] * SCALEF; if (n0 + wn + lr > grow)      t0 = NEGBIG;
      float t1 = s1[j] * SCALEF; if (n0 + wn + 16 + lr > grow) t1 = NEGBIG;
      pv0[j] = t0; pv1[j] = t1;
      float v = fmaxf(t0, t1);
      v = fmaxf(v, __shfl_xor(v, 1)); v = fmaxf(v, __shfl_xor(v, 2));
      v = fmaxf(v, __shfl_xor(v, 4)); v = fmaxf(v, __shfl_xor(v, 8));
      wmaxp[(wave & 1) * 32 + wm + (kh << 2) + j] = v;
    }
    lgkm_barrier();

    float tmax[4]; bool need = false;
#pragma unroll
    for (int j = 0; j < 4; ++j) {
      const int rl = wm + (kh << 2) + j;
      tmax[j] = fmaxf(wmaxp[rl], wmaxp[32 + rl]);
      need |= (tmax[j] > m_[j] + 8.f);
    }
    if (__ballot(need)) {
#pragma unroll
      for (int j = 0; j < 4; ++j) {
        const float mn = fmaxf(m_[j], tmax[j]);
        const float al = __expf(m_[j] - mn);
        m_[j] = mn; l_[j] *= al; o0[j] *= al; o1[j] *= al;
      }
    }
#pragma unroll
    for (int j = 0; j < 4; ++j) {
      const float p0 = __expf(pv0[j] - m_[j]);
      const float p1 = __expf(pv1[j] - m_[j]);
      float rs = p0 + p1;
      rs += __shfl_xor(rs, 1); rs += __shfl_xor(rs, 2);
      rs += __shfl_xor(rs, 4); rs += __shfl_xor(rs, 8);
      const int rl = wm + (kh << 2) + j;
      wsump[(wave & 1) * 32 + rl] = rs;
      const int pc0 = wn + lr, pc1 = wn + 16 + lr;
      Ps[pc0 >> 3][rl][pc0 & 7] = (__bf16)p0;
      Ps[pc1 >> 3][rl][pc1 & 7] = (__bf16)p1;
    }
    lgkm_barrier();

#pragma unroll
    for (int j = 0; j < 4; ++j) {
      const int rl = wm + (kh << 2) + j;
      l_[j] += wsump[rl] + wsump[32 + rl];
    }
#pragma unroll
    for (int ks = 0; ks < 2; ++ks) {
      const int kidx = ks * 4 + kh;
      bf16x8 a  = *(const bf16x8*)&Ps[kidx][wm + lr][0];
      bf16x8 b0 = *(const bf16x8*)&Vs[cur][kidx][wn + lr][0];
      bf16x8 b1 = *(const bf16x8*)&Vs[cur][kidx][wn + 16 + lr][0];
      o0 = MFMA(a, b0, o0); o1 = MFMA(a, b1, o1);
    }
    __builtin_amdgcn_s_barrier();
    cur ^= 1;
  }

#pragma unroll
  for (int j = 0; j < 4; ++j) {
    const int row = m0 + wm + (kh << 2) + j;
    const float inv = 1.0f / l_[j];
    y2[((size_t)(b * TSEQ) + row) * EDIM + h * HDIM + wn + lr]      = (__bf16)(o0[j] * inv);
    y2[((size_t)(b * TSEQ) + row) * EDIM + h * HDIM + wn + 16 + lr] = (__bf16)(o1[j] * inv);
  }
}

// ---------------------------------------------------------------- launcher
extern "C" void kernel_launch(void* const* d_in, const int* in_sizes, int n_in,
                              void* d_out, int out_size, void* d_ws, size_t ws_size,
                              hipStream_t stream) {
  const int*   tokens  = (const int*)d_in[0];
  const float* emb     = (const float*)d_in[1];
  const float* Wqkv    = (const float*)d_in[2];
  const float* bqkv    = (const float*)d_in[3];
  const float* Wo      = (const float*)d_in[4];
  const float* bo      = (const float*)d_in[5];
  const float* W1      = (const float*)d_in[6];
  const float* b1      = (const float*)d_in[7];
  const float* W3      = (const float*)d_in[8];
  const float* b3      = (const float*)d_in[9];
  const float* W2w     = (const float*)d_in[10];
  const float* b2      = (const float*)d_in[11];
  const float* g_mha   = (const float*)d_in[12];
  const float* g_ff    = (const float*)d_in[13];
  const float* g_final = (const float*)d_in[14];
  const float* Wout    = (const float*)d_in[15];
  const float* bout    = (const float*)d_in[16];
  float* out = (float*)d_out;

  char* base = (char*)d_ws;
  size_t off = 0;
  auto alloc = [&](size_t bytes) { char* p = base + off; off = (off + bytes + 255) & ~(size_t)255; return p; };
  float*  x    = (float*)alloc(4u << 20);
  float*  part = (float*)alloc(4096);
  __bf16* ybf  = (__bf16*)alloc(2u << 20);
  __bf16* qbf  = (__bf16*)alloc(2u << 20);
  __bf16* kbf  = (__bf16*)alloc(2u << 20);
  __bf16* vbT  = (__bf16*)alloc(2u << 20);
  __bf16* y2bf = (__bf16*)alloc(2u << 20);
  __bf16* ubf  = (__bf16*)alloc((size_t)MTOK * DPAD * 2);
  float*  pbuf = (float*)alloc((size_t)4 * NELEM * 4);
  __bf16* WoutT = (__bf16*)alloc((size_t)8192 * 1024 * 2);
  __bf16* qkvT = (__bf16*)alloc((size_t)NLAYER * 3072 * 1024 * 2);
  __bf16* woT  = (__bf16*)alloc((size_t)NLAYER * 1024 * 1024 * 2);
  __bf16* w1T  = (__bf16*)alloc((size_t)NLAYER * DPAD * 1024 * 2);
  __bf16* w3T  = (__bf16*)alloc((size_t)NLAYER * DPAD * 1024 * 2);
  __bf16* w2T  = (__bf16*)alloc((size_t)NLAYER * 1024 * DPAD * 2);

  ConvW cw;
  cw.Wqkv = Wqkv; cw.Wo = Wo; cw.W1 = W1; cw.W3 = W3; cw.W2w = W2w;
  cw.g_mha = g_mha; cw.g_ff = g_ff; cw.Wout = Wout; cw.g_final = g_final;
  cw.qkvT = qkvT; cw.woT = woT; cw.w1T = w1T; cw.w3T = w3T; cw.w2T = w2T;
  cw.WoutT = WoutT;

  k_embed<<<MTOK, 256, 0, stream>>>(tokens, emb, x);
  k_conv0<<<LCONV, 256, 0, stream>>>(cw);              // layer-0 weights only
  k_red1f<0><<<RGRID, 256, 0, stream>>>(x, nullptr, nullptr, part, ybf);

  for (int l = 0; l < NLAYER; ++l) {
    // carriers convert layer l+1 (or the head when l==23)
    const int co = (l + 1 < NLAYER) ? (l + 1) * LCONV : ACONV;
    const int cn = (l + 1 < NLAYER) ? 772 : 512;       // 4 carrier groups/layer
    // --- MHA ---
    mm<64, 0, 1><<<384 + cn, 256, 0, stream>>>(
        ybf, qkvT + (size_t)l * 3072 * 1024, nullptr,
        bqkv + (size_t)l * 3 * EDIM, nullptr, part,
        nullptr, nullptr, qbf, kbf, vbT, 3072, 1024, 1024, 1024,
        48, 8, 1, cw, co);
    k_flash<<<512 + cn, 256, 0, stream>>>(qbf, kbf, vbT, y2bf, cw, co + cn);
    mm<64, 1, 0><<<512, 256, 0, stream>>>(
        y2bf, woT + (size_t)l * 1024 * 1024, nullptr,
        nullptr, nullptr, nullptr,
        pbuf, nullptr, nullptr, nullptr, nullptr, 1024, 1024, 1024, 1024,
        16, 8, 4, cw, 0);
    // --- SwiGLU FFN ---
    k_red1f<4><<<RGRID, 256, 0, stream>>>(x, pbuf, bo + (size_t)l * EDIM, part, ybf);
    mm<64, 2, 1><<<344 + cn, 256, 0, stream>>>(
        ybf, w1T + (size_t)l * DPAD * 1024, w3T + (size_t)l * DPAD * 1024,
        b1 + (size_t)l * DFFDIM, b3 + (size_t)l * DFFDIM, part,
        nullptr, ubf, nullptr, nullptr, nullptr, DFFDIM, 1024, 1024, 1024,
        43, 8, 1, cw, co + 2 * cn);
    mm<64, 1, 0><<<512 + cn, 256, 0, stream>>>(
        ubf, w2T + (size_t)l * 1024 * DPAD, nullptr,
        nullptr, nullptr, nullptr,
        pbuf, nullptr, nullptr, nullptr, nullptr, 1024, DPAD, DPAD, DPAD,
        16, 8, 4, cw, co + 3 * cn);
    // fold w2 partials + b2; emits next layer's (or head's) ybf/part
    k_red1f<4><<<RGRID, 256, 0, stream>>>(x, pbuf, b2 + (size_t)l * EDIM, part, ybf);
  }

  // --- vocab head ---
  mm<128, 3, 1><<<512, 256, 0, stream>>>(
      ybf, WoutT, nullptr, bout, nullptr, part,
      out, nullptr, nullptr, nullptr, nullptr, VOCAB, 1024, 1024, 1024,
      64, 8, 1, cw, 0);
}